// Round 12
// baseline (647.070 us; speedup 1.0000x reference)
//
#include <hip/hip_runtime.h>

#define TT 64
#define NN 512
#define DD 128

typedef __attribute__((ext_vector_type(8))) short bf16x8;
typedef __attribute__((ext_vector_type(4))) float f32x4;

__device__ __forceinline__ unsigned cvtpk(float lo, float hi) {
  unsigned r;
  asm("v_cvt_pk_bf16_f32 %0, %1, %2" : "=v"(r) : "v"(lo), "v"(hi));
  return r;
}

// XOR-swizzled LDS index helpers (units: unsigned short elements).
__device__ __forceinline__ int swz128(int row, int col) {
  return row * 128 + (((col >> 3) ^ (row & 15)) << 3) + (col & 7);
}
__device__ __forceinline__ int swz64(int row, int col) {
  return row * 64 + (((col >> 3) ^ (row & 7)) << 3) + (col & 7);
}

// Barrier with LDS-only drain: global loads stay in flight across it.
__device__ __forceinline__ void bar() {
  asm volatile("s_waitcnt lgkmcnt(0)" ::: "memory");
  __builtin_amdgcn_s_barrier();
  asm volatile("" ::: "memory");
}

// 16-lane (DPP-row) sum via row_ror butterflies — VALU pipe, no LDS traffic.
__device__ __forceinline__ float red16(float s) {
  int t;
  t = __builtin_amdgcn_update_dpp(0, __float_as_int(s), 0x121, 0xf, 0xf, false);
  s += __int_as_float(t);
  t = __builtin_amdgcn_update_dpp(0, __float_as_int(s), 0x122, 0xf, 0xf, false);
  s += __int_as_float(t);
  t = __builtin_amdgcn_update_dpp(0, __float_as_int(s), 0x124, 0xf, 0xf, false);
  s += __int_as_float(t);
  t = __builtin_amdgcn_update_dpp(0, __float_as_int(s), 0x128, 0xf, 0xf, false);
  s += __int_as_float(t);
  return s;
}

// transpose fp32 [K][N] -> bf16 [N][K]
__global__ void wprep(const float* __restrict__ src, unsigned short* __restrict__ dst,
                      int K, int Nn) {
  int idx = blockIdx.x * 256 + threadIdx.x;
  if (idx >= K * Nn) return;
  int n = idx / K, k = idx - n * K;
  float f = src[k * Nn + n];
  unsigned u = __float_as_uint(f);
  u += 0x7fffu + ((u >> 16) & 1u);
  dst[idx] = (unsigned short)(u >> 16);
}

#define KSCL 0.36067376022224085f   // 0.25 * log2(e), folded into K epilogue

__global__ __launch_bounds__(512, 4)
void fused_layer(const float* __restrict__ x_in, const float* __restrict__ ste,
                 const float* __restrict__ g1, const float* __restrict__ b1,
                 const float* __restrict__ g2, const float* __restrict__ b2,
                 const unsigned short* __restrict__ wqt, const float* __restrict__ bq,
                 const unsigned short* __restrict__ wkt, const float* __restrict__ bk,
                 const unsigned short* __restrict__ wvt, const float* __restrict__ bv,
                 const unsigned short* __restrict__ wo1t, const float* __restrict__ bo1,
                 const unsigned short* __restrict__ wo2t, const float* __restrict__ bo2,
                 const unsigned short* __restrict__ wf1t, const float* __restrict__ bf1,
                 const unsigned short* __restrict__ wf2t, const float* __restrict__ bf2,
                 float* __restrict__ out) {
  __shared__ __align__(16) unsigned short smem[32768];  // 64 KB

  const int tid = threadIdx.x;
  const int lane = tid & 63;
  const int w  = tid >> 6;         // wave 0..7
  const int lg = lane >> 4;        // 0..3
  const int li = lane & 15;
  const int hc = w * 16;           // col-strip base (K/V/Q) == head base
  const int tw = w & 3;            // tail row group
  const int ch = w >> 2;           // tail store col half
  const int R  = tw * 16;          // tail rows R..R+15

  const int blk = blockIdx.x;
  const int b = blk >> 9;          // N=512
  const int n = blk & 511;
  const int rs = NN * DD;
  const float* xbase = x_in + (b * TT * NN + n) * DD;
  const float* sbase = ste + (b * TT * NN + n) * DD;

  // Region plan (3 barriers: B0, B0e, B2):
  //  [0..16384)      X2s [64][256] (xnorm|STE), reads end at B0e
  //  [0..8192)       post-B0e: Qb  (Q col-strips) [64][128]
  //  [8192..16384)   post-B0e: AOb (attention out) [64][128]
  //  [16384..24576)  Kb [64][128]  — NOT an overlay: written immediately
  //  [24576..32768)  Vt [128][64]  — NOT an overlay: written immediately
  //  [16384..32768)  post-B2: per-wave scratch Sp = 16384 + w*2048, [16][128]
  unsigned short* X2s = smem;
  unsigned short* Qb  = smem;
  unsigned short* AOb = smem + 8192;
  unsigned short* Kb  = smem + 16384;
  unsigned short* Vt  = smem + 24576;
  unsigned short* Sp  = smem + 16384 + w * 2048;

  #define SWZ256(row, col) ((row) * 256 + ((((col) >> 3) ^ ((row) & 15)) << 3) + ((col) & 7))

  // ---------------- LN1 + STE -> X2 (all input loads hoisted) --------------
  {
    const int t0 = w * 8 + lg;
    const float* xr0 = xbase + t0 * rs + li * 8;
    const float* xr1 = xbase + (t0 + 4) * rs + li * 8;
    const float* sr0 = sbase + t0 * rs + li * 8;
    const float* sr1 = sbase + (t0 + 4) * rs + li * 8;
    float4 xA0 = *(const float4*)(xr0);
    float4 xB0 = *(const float4*)(xr0 + 4);
    float4 xA1 = *(const float4*)(xr1);
    float4 xB1 = *(const float4*)(xr1 + 4);
    float4 sA0 = *(const float4*)(sr0);
    float4 sB0 = *(const float4*)(sr0 + 4);
    float4 sA1 = *(const float4*)(sr1);
    float4 sB1 = *(const float4*)(sr1 + 4);
    float4 gA = *(const float4*)(g1 + li * 8);
    float4 gB = *(const float4*)(g1 + li * 8 + 4);
    float4 bA = *(const float4*)(b1 + li * 8);
    float4 bB = *(const float4*)(b1 + li * 8 + 4);

    {  // row t0
      float s1 = xA0.x + xA0.y + xA0.z + xA0.w + xB0.x + xB0.y + xB0.z + xB0.w;
      float s2 = xA0.x * xA0.x + xA0.y * xA0.y + xA0.z * xA0.z + xA0.w * xA0.w +
                 xB0.x * xB0.x + xB0.y * xB0.y + xB0.z * xB0.z + xB0.w * xB0.w;
      s1 = red16(s1); s2 = red16(s2);
      float mean = s1 * (1.0f / 128.0f);
      float var = fmaxf((s2 - s1 * mean) * (1.0f / 127.0f), 0.0f);  // ddof=1
      float inv = 1.0f / (sqrtf(var) + 1e-6f);
      unsigned o01 = cvtpk(gA.x * (xA0.x - mean) * inv + bA.x, gA.y * (xA0.y - mean) * inv + bA.y);
      unsigned o23 = cvtpk(gA.z * (xA0.z - mean) * inv + bA.z, gA.w * (xA0.w - mean) * inv + bA.w);
      unsigned o45 = cvtpk(gB.x * (xB0.x - mean) * inv + bB.x, gB.y * (xB0.y - mean) * inv + bB.y);
      unsigned o67 = cvtpk(gB.z * (xB0.z - mean) * inv + bB.z, gB.w * (xB0.w - mean) * inv + bB.w);
      *(uint4*)(X2s + SWZ256(t0, li * 8)) = (uint4){o01, o23, o45, o67};
    }
    {  // row t0+4
      float s1 = xA1.x + xA1.y + xA1.z + xA1.w + xB1.x + xB1.y + xB1.z + xB1.w;
      float s2 = xA1.x * xA1.x + xA1.y * xA1.y + xA1.z * xA1.z + xA1.w * xA1.w +
                 xB1.x * xB1.x + xB1.y * xB1.y + xB1.z * xB1.z + xB1.w * xB1.w;
      s1 = red16(s1); s2 = red16(s2);
      float mean = s1 * (1.0f / 128.0f);
      float var = fmaxf((s2 - s1 * mean) * (1.0f / 127.0f), 0.0f);
      float inv = 1.0f / (sqrtf(var) + 1e-6f);
      unsigned o01 = cvtpk(gA.x * (xA1.x - mean) * inv + bA.x, gA.y * (xA1.y - mean) * inv + bA.y);
      unsigned o23 = cvtpk(gA.z * (xA1.z - mean) * inv + bA.z, gA.w * (xA1.w - mean) * inv + bA.w);
      unsigned o45 = cvtpk(gB.x * (xB1.x - mean) * inv + bB.x, gB.y * (xB1.y - mean) * inv + bB.y);
      unsigned o67 = cvtpk(gB.z * (xB1.z - mean) * inv + bB.z, gB.w * (xB1.w - mean) * inv + bB.w);
      *(uint4*)(X2s + SWZ256(t0 + 4, li * 8)) = (uint4){o01, o23, o45, o67};
    }
    *(uint4*)(X2s + SWZ256(t0, 128 + li * 8)) =
        (uint4){cvtpk(sA0.x, sA0.y), cvtpk(sA0.z, sA0.w), cvtpk(sB0.x, sB0.y), cvtpk(sB0.z, sB0.w)};
    *(uint4*)(X2s + SWZ256(t0 + 4, 128 + li * 8)) =
        (uint4){cvtpk(sA1.x, sA1.y), cvtpk(sA1.z, sA1.w), cvtpk(sB1.x, sB1.y), cvtpk(sB1.z, sB1.w)};
  }

  bar();  // B0: X2 visible

  // ---------------- V-pass (cols hc..hc+15), immediate epi -> Vt -----------
  {
    const unsigned short* vB = wvt + hc * 256;
    f32x4 va[4];
    #pragma unroll
    for (int rg = 0; rg < 4; ++rg) va[rg] = (f32x4){0, 0, 0, 0};
    #pragma unroll
    for (int kk = 0; kk < 8; ++kk) {
      bf16x8 bc = *(const bf16x8*)(vB + li * 256 + kk * 32 + lg * 8);
      #pragma unroll
      for (int rg = 0; rg < 4; ++rg) {
        bf16x8 af = *(const bf16x8*)(X2s + SWZ256(rg * 16 + li, kk * 32 + lg * 8));
        va[rg] = __builtin_amdgcn_mfma_f32_16x16x32_bf16(af, bc, va[rg], 0, 0, 0);
      }
    }
    float bvv = bv[hc + li];
    int d = hc + li;
    #pragma unroll
    for (int rg = 0; rg < 4; ++rg) {
      float v0 = fmaxf(va[rg][0] + bvv, 0.0f);
      float v1 = fmaxf(va[rg][1] + bvv, 0.0f);
      float v2 = fmaxf(va[rg][2] + bvv, 0.0f);
      float v3 = fmaxf(va[rg][3] + bvv, 0.0f);
      uint2 pv; pv.x = cvtpk(v0, v1); pv.y = cvtpk(v2, v3);
      *(uint2*)(Vt + swz64(d, rg * 16 + lg * 4)) = pv;
    }
  }

  // ---------------- K-pass (cols hc..hc+15), immediate epi -> Kb -----------
  {
    const unsigned short* kB = wkt + hc * 256;
    f32x4 ka[4];
    #pragma unroll
    for (int rg = 0; rg < 4; ++rg) ka[rg] = (f32x4){0, 0, 0, 0};
    #pragma unroll
    for (int kk = 0; kk < 8; ++kk) {
      bf16x8 bc = *(const bf16x8*)(kB + li * 256 + kk * 32 + lg * 8);
      #pragma unroll
      for (int rg = 0; rg < 4; ++rg) {
        bf16x8 af = *(const bf16x8*)(X2s + SWZ256(rg * 16 + li, kk * 32 + lg * 8));
        ka[rg] = __builtin_amdgcn_mfma_f32_16x16x32_bf16(af, bc, ka[rg], 0, 0, 0);
      }
    }
    float bkv = bk[hc + li];
    int col = hc + li;
    #pragma unroll
    for (int rg = 0; rg < 4; ++rg) {
      float k0 = fmaxf(ka[rg][0] + bkv, 0.0f) * KSCL;
      float k1 = fmaxf(ka[rg][1] + bkv, 0.0f) * KSCL;
      float k2 = fmaxf(ka[rg][2] + bkv, 0.0f) * KSCL;
      float k3 = fmaxf(ka[rg][3] + bkv, 0.0f) * KSCL;
      unsigned p01 = cvtpk(k0, k1), p23 = cvtpk(k2, k3);
      Kb[swz128(rg * 16 + lg * 4 + 0, col)] = (unsigned short)p01;
      Kb[swz128(rg * 16 + lg * 4 + 1, col)] = (unsigned short)(p01 >> 16);
      Kb[swz128(rg * 16 + lg * 4 + 2, col)] = (unsigned short)p23;
      Kb[swz128(rg * 16 + lg * 4 + 3, col)] = (unsigned short)(p23 >> 16);
    }
  }

  // ---------------- Q-pass (cols hc..hc+15) --------------------------------
  f32x4 qa[4];
  #pragma unroll
  for (int rg = 0; rg < 4; ++rg) qa[rg] = (f32x4){0, 0, 0, 0};
  {
    const unsigned short* qB = wqt + hc * 256;
    #pragma unroll
    for (int kk = 0; kk < 8; ++kk) {
      bf16x8 bc = *(const bf16x8*)(qB + li * 256 + kk * 32 + lg * 8);
      #pragma unroll
      for (int rg = 0; rg < 4; ++rg) {
        bf16x8 af = *(const bf16x8*)(X2s + SWZ256(rg * 16 + li, kk * 32 + lg * 8));
        qa[rg] = __builtin_amdgcn_mfma_f32_16x16x32_bf16(af, bc, qa[rg], 0, 0, 0);
      }
    }
  }

  bar();  // B0e: ALL X2 reads done -> Qb/AOb overlays live

  // Q epilogue -> Qb (own col strip; consumed only by this wave)
  {
    float bqv = bq[hc + li];
    int col = hc + li;
    #pragma unroll
    for (int rg = 0; rg < 4; ++rg) {
      float v0 = fmaxf(qa[rg][0] + bqv, 0.0f);
      float v1 = fmaxf(qa[rg][1] + bqv, 0.0f);
      float v2 = fmaxf(qa[rg][2] + bqv, 0.0f);
      float v3 = fmaxf(qa[rg][3] + bqv, 0.0f);
      unsigned p01 = cvtpk(v0, v1), p23 = cvtpk(v2, v3);
      Qb[swz128(rg * 16 + lg * 4 + 0, col)] = (unsigned short)p01;
      Qb[swz128(rg * 16 + lg * 4 + 1, col)] = (unsigned short)(p01 >> 16);
      Qb[swz128(rg * 16 + lg * 4 + 2, col)] = (unsigned short)p23;
      Qb[swz128(rg * 16 + lg * 4 + 3, col)] = (unsigned short)(p23 >> 16);
    }
  }

  // ---------------- causal attention, head w (all strips wave-local) -------
  {
    const bf16x8 zf = (bf16x8){0, 0, 0, 0, 0, 0, 0, 0};
    bf16x8 kf[4], vf[2];
    #pragma unroll
    for (int pt = 0; pt < 4; ++pt)
      kf[pt] = (lg < 2) ? *(const bf16x8*)(Kb + swz128(pt * 16 + li, hc + lg * 8)) : zf;
    #pragma unroll
    for (int ks = 0; ks < 2; ++ks)
      vf[ks] = *(const bf16x8*)(Vt + swz64(hc + li, ks * 32 + lg * 8));

    #pragma unroll
    for (int qt = 0; qt < 4; ++qt) {
      bf16x8 qf = (lg < 2) ? *(const bf16x8*)(Qb + swz128(qt * 16 + li, hc + lg * 8)) : zf;
      f32x4 st[4];
      #pragma unroll
      for (int pt = 0; pt < 4; ++pt)
        if (pt <= qt)
          st[pt] = __builtin_amdgcn_mfma_f32_16x16x32_bf16(kf[pt], qf, (f32x4){0, 0, 0, 0}, 0, 0, 0);

      float ssum = 0.0f;
      unsigned pa[4], pb[4];
      #pragma unroll
      for (int pt = 0; pt < 4; ++pt) {
        if (pt > qt) { pa[pt] = 0; pb[pt] = 0; continue; }
        float e0 = exp2f(st[pt][0]);
        float e1 = exp2f(st[pt][1]);
        float e2 = exp2f(st[pt][2]);
        float e3 = exp2f(st[pt][3]);
        if (pt == qt) {  // diagonal tile: mask p_local > q_local
          e0 = (4 * lg + 0 > li) ? 0.0f : e0;
          e1 = (4 * lg + 1 > li) ? 0.0f : e1;
          e2 = (4 * lg + 2 > li) ? 0.0f : e2;
          e3 = (4 * lg + 3 > li) ? 0.0f : e3;
        }
        ssum += e0 + e1 + e2 + e3;
        pa[pt] = cvtpk(e0, e1);
        pb[pt] = cvtpk(e2, e3);
      }
      ssum += __shfl_xor(ssum, 16, 64);
      ssum += __shfl_xor(ssum, 32, 64);
      float rinv = 1.0f / ssum;

      f32x4 oa = (f32x4){0, 0, 0, 0};
      #pragma unroll
      for (int ks = 0; ks < 2; ++ks) {
        if (ks * 2 > qt) continue;
        unsigned x = pa[2 * ks], y = pa[2 * ks + 1];
        asm("v_permlane32_swap_b32 %0, %1" : "+v"(x), "+v"(y));
        asm("v_permlane16_swap_b32 %0, %1" : "+v"(x), "+v"(y));
        unsigned u2 = pb[2 * ks], v2 = pb[2 * ks + 1];
        asm("v_permlane32_swap_b32 %0, %1" : "+v"(u2), "+v"(v2));
        asm("v_permlane16_swap_b32 %0, %1" : "+v"(u2), "+v"(v2));
        union { unsigned uw[4]; bf16x8 h; } pu;
        pu.uw[0] = x; pu.uw[1] = u2; pu.uw[2] = y; pu.uw[3] = v2;
        oa = __builtin_amdgcn_mfma_f32_16x16x32_bf16(vf[ks], pu.h, oa, 0, 0, 0);
      }
      uint2 ov;
      ov.x = cvtpk(oa[0] * rinv, oa[1] * rinv);
      ov.y = cvtpk(oa[2] * rinv, oa[3] * rinv);
      *(uint2*)(AOb + swz128(qt * 16 + li, hc + lg * 4)) = ov;
    }
  }

  // residual x loads issued pre-B2 (survive the lgkm-only barrier)
  float xr[8][4];
  #pragma unroll
  for (int ct = 0; ct < 8; ++ct)
    #pragma unroll
    for (int r = 0; r < 4; ++r)
      xr[ct][r] = xbase[(R + lg * 4 + r) * rs + ct * 16 + li];

  bar();  // B2: AO visible; Kb/Vt dead -> Sp scratch live. Last barrier.

  // ================= barrier-free tail: rows R..R+15, full width ===========
  bf16x8 af4[4];
  #pragma unroll
  for (int kk = 0; kk < 4; ++kk)
    af4[kk] = *(const bf16x8*)(AOb + swz128(R + li, kk * 32 + lg * 8));

  // O1 full-width
  f32x4 a1[8];
  #pragma unroll
  for (int i = 0; i < 8; ++i) a1[i] = (f32x4){0, 0, 0, 0};
  #pragma unroll
  for (int kk = 0; kk < 4; ++kk)
    #pragma unroll
    for (int ct = 0; ct < 8; ++ct)
      a1[ct] = __builtin_amdgcn_mfma_f32_16x16x32_bf16(
          af4[kk], *(const bf16x8*)(wo1t + (ct * 16 + li) * 128 + kk * 32 + lg * 8),
          a1[ct], 0, 0, 0);
  #pragma unroll
  for (int ct = 0; ct < 8; ++ct) {  // epi -> private Sp (H1)
    float bvv = bo1[ct * 16 + li];
    int col = ct * 16 + li;
    float v0 = fmaxf(a1[ct][0] + bvv, 0.0f);
    float v1 = fmaxf(a1[ct][1] + bvv, 0.0f);
    float v2 = fmaxf(a1[ct][2] + bvv, 0.0f);
    float v3 = fmaxf(a1[ct][3] + bvv, 0.0f);
    unsigned p01 = cvtpk(v0, v1), p23 = cvtpk(v2, v3);
    Sp[swz128(lg * 4 + 0, col)] = (unsigned short)p01;
    Sp[swz128(lg * 4 + 1, col)] = (unsigned short)(p01 >> 16);
    Sp[swz128(lg * 4 + 2, col)] = (unsigned short)p23;
    Sp[swz128(lg * 4 + 3, col)] = (unsigned short)(p23 >> 16);
  }

  // O2 full-width (H1 from private Sp; same-wave DS is in-order)
  #pragma unroll
  for (int kk = 0; kk < 4; ++kk)
    af4[kk] = *(const bf16x8*)(Sp + swz128(li, kk * 32 + lg * 8));
  f32x4 ya[8];
  #pragma unroll
  for (int i = 0; i < 8; ++i) ya[i] = (f32x4){0, 0, 0, 0};
  #pragma unroll
  for (int kk = 0; kk < 4; ++kk)
    #pragma unroll
    for (int ct = 0; ct < 8; ++ct)
      ya[ct] = __builtin_amdgcn_mfma_f32_16x16x32_bf16(
          af4[kk], *(const bf16x8*)(wo2t + (ct * 16 + li) * 128 + kk * 32 + lg * 8),
          ya[ct], 0, 0, 0);

  float x2r[8][4];
  #pragma unroll
  for (int ct = 0; ct < 8; ++ct) {
    float bvv = bo2[ct * 16 + li];
    #pragma unroll
    for (int r = 0; r < 4; ++r)
      x2r[ct][r] = ya[ct][r] + bvv + xr[ct][r];
  }

  // ---------------- LN2 (fully wave-local) ---------------------------------
  float g2v[8], b2v[8];
  #pragma unroll
  for (int ct = 0; ct < 8; ++ct) {
    g2v[ct] = g2[ct * 16 + li];
    b2v[ct] = b2[ct * 16 + li];
  }
  float s1p[4] = {0, 0, 0, 0}, s2p[4] = {0, 0, 0, 0};
  #pragma unroll
  for (int ct = 0; ct < 8; ++ct)
    #pragma unroll
    for (int r = 0; r < 4; ++r) {
      float v = x2r[ct][r];
      s1p[r] += v; s2p[r] += v * v;
    }
  float mean_[4], inv_[4];
  #pragma unroll
  for (int r = 0; r < 4; ++r) {
    float s1 = red16(s1p[r]);
    float s2 = red16(s2p[r]);
    float mean = s1 * (1.0f / 128.0f);
    float var = fmaxf((s2 - s1 * mean) * (1.0f / 127.0f), 0.0f);
    mean_[r] = mean;
    inv_[r] = 1.0f / (sqrtf(var) + 1e-6f);
  }
  #pragma unroll
  for (int ct = 0; ct < 8; ++ct) {  // Xn2 -> private Sp (H1 dead)
    int col = ct * 16 + li;
    float xn0 = g2v[ct] * (x2r[ct][0] - mean_[0]) * inv_[0] + b2v[ct];
    float xn1 = g2v[ct] * (x2r[ct][1] - mean_[1]) * inv_[1] + b2v[ct];
    float xn2 = g2v[ct] * (x2r[ct][2] - mean_[2]) * inv_[2] + b2v[ct];
    float xn3 = g2v[ct] * (x2r[ct][3] - mean_[3]) * inv_[3] + b2v[ct];
    unsigned p01 = cvtpk(xn0, xn1), p23 = cvtpk(xn2, xn3);
    Sp[swz128(lg * 4 + 0, col)] = (unsigned short)p01;
    Sp[swz128(lg * 4 + 1, col)] = (unsigned short)(p01 >> 16);
    Sp[swz128(lg * 4 + 2, col)] = (unsigned short)p23;
    Sp[swz128(lg * 4 + 3, col)] = (unsigned short)(p23 >> 16);
  }
  // keep only the store half of x2r live through the FFN
  float x2k[4][4];
  #pragma unroll
  for (int c4 = 0; c4 < 4; ++c4)
    #pragma unroll
    for (int r = 0; r < 4; ++r)
      x2k[c4][r] = x2r[ch * 4 + c4][r];

  // ---------------- FFN ----------------------------------------------------
  #pragma unroll
  for (int kk = 0; kk < 4; ++kk)
    af4[kk] = *(const bf16x8*)(Sp + swz128(li, kk * 32 + lg * 8));
  f32x4 f1a[8];
  #pragma unroll
  for (int i = 0; i < 8; ++i) f1a[i] = (f32x4){0, 0, 0, 0};
  #pragma unroll
  for (int kk = 0; kk < 4; ++kk)
    #pragma unroll
    for (int ct = 0; ct < 8; ++ct)
      f1a[ct] = __builtin_amdgcn_mfma_f32_16x16x32_bf16(
          af4[kk], *(const bf16x8*)(wf1t + (ct * 16 + li) * 128 + kk * 32 + lg * 8),
          f1a[ct], 0, 0, 0);
  #pragma unroll
  for (int ct = 0; ct < 8; ++ct) {  // epi -> private Sp (Hf)
    float bvv = bf1[ct * 16 + li];
    int col = ct * 16 + li;
    float v0 = fmaxf(f1a[ct][0] + bvv, 0.0f);
    float v1 = fmaxf(f1a[ct][1] + bvv, 0.0f);
    float v2 = fmaxf(f1a[ct][2] + bvv, 0.0f);
    float v3 = fmaxf(f1a[ct][3] + bvv, 0.0f);
    unsigned p01 = cvtpk(v0, v1), p23 = cvtpk(v2, v3);
    Sp[swz128(lg * 4 + 0, col)] = (unsigned short)p01;
    Sp[swz128(lg * 4 + 1, col)] = (unsigned short)(p01 >> 16);
    Sp[swz128(lg * 4 + 2, col)] = (unsigned short)p23;
    Sp[swz128(lg * 4 + 3, col)] = (unsigned short)(p23 >> 16);
  }

  // F2: only the 4 col-tiles this wave stores (ch half)
  #pragma unroll
  for (int kk = 0; kk < 4; ++kk)
    af4[kk] = *(const bf16x8*)(Sp + swz128(li, kk * 32 + lg * 8));
  f32x4 f2a[4];
  #pragma unroll
  for (int i = 0; i < 4; ++i) f2a[i] = (f32x4){0, 0, 0, 0};
  #pragma unroll
  for (int kk = 0; kk < 4; ++kk)
    #pragma unroll
    for (int c4 = 0; c4 < 4; ++c4)
      f2a[c4] = __builtin_amdgcn_mfma_f32_16x16x32_bf16(
          af4[kk],
          *(const bf16x8*)(wf2t + (ch * 64 + c4 * 16 + li) * 128 + kk * 32 + lg * 8),
          f2a[c4], 0, 0, 0);

  float* obase = out + (b * TT * NN + n) * DD;
  #pragma unroll
  for (int c4 = 0; c4 < 4; ++c4) {
    float bvv = bf2[ch * 64 + c4 * 16 + li];
    #pragma unroll
    for (int r = 0; r < 4; ++r)
      obase[(R + lg * 4 + r) * rs + ch * 64 + c4 * 16 + li] =
          x2k[c4][r] + fmaxf(f2a[c4][r] + bvv, 0.0f);
  }
  #undef SWZ256
}

extern "C" void kernel_launch(void* const* d_in, const int* in_sizes, int n_in,
                              void* d_out, int out_size, void* d_ws, size_t ws_size,
                              hipStream_t stream) {
  const float* x   = (const float*)d_in[0];
  const float* ste = (const float*)d_in[1];
  const float* g1 = (const float*)d_in[3];
  const float* b1 = (const float*)d_in[4];
  const float* g2 = (const float*)d_in[5];
  const float* b2 = (const float*)d_in[6];
  const float* Wq = (const float*)d_in[7];   const float* bq  = (const float*)d_in[8];
  const float* Wk = (const float*)d_in[9];   const float* bk  = (const float*)d_in[10];
  const float* Wv = (const float*)d_in[11];  const float* bv  = (const float*)d_in[12];
  const float* Wo1 = (const float*)d_in[13]; const float* bo1 = (const float*)d_in[14];
  const float* Wo2 = (const float*)d_in[15]; const float* bo2 = (const float*)d_in[16];
  const float* Wf1 = (const float*)d_in[17]; const float* bf1 = (const float*)d_in[18];
  const float* Wf2 = (const float*)d_in[19]; const float* bf2 = (const float*)d_in[20];
  float* out = (float*)d_out;

  unsigned short* wsu = (unsigned short*)d_ws;
  unsigned short* wq_t  = wsu;             // [128][256]
  unsigned short* wk_t  = wsu + 32768;
  unsigned short* wv_t  = wsu + 65536;
  unsigned short* wo1_t = wsu + 98304;     // [128][128]
  unsigned short* wo2_t = wsu + 114688;
  unsigned short* wf1_t = wsu + 131072;
  unsigned short* wf2_t = wsu + 147456;

  hipLaunchKernelGGL(wprep, dim3(128), dim3(256), 0, stream, Wq, wq_t, 256, 128);
  hipLaunchKernelGGL(wprep, dim3(128), dim3(256), 0, stream, Wk, wk_t, 256, 128);
  hipLaunchKernelGGL(wprep, dim3(128), dim3(256), 0, stream, Wv, wv_t, 256, 128);
  hipLaunchKernelGGL(wprep, dim3(64), dim3(256), 0, stream, Wo1, wo1_t, 128, 128);
  hipLaunchKernelGGL(wprep, dim3(64), dim3(256), 0, stream, Wo2, wo2_t, 128, 128);
  hipLaunchKernelGGL(wprep, dim3(64), dim3(256), 0, stream, Wf1, wf1_t, 128, 128);
  hipLaunchKernelGGL(wprep, dim3(64), dim3(256), 0, stream, Wf2, wf2_t, 128, 128);

  hipLaunchKernelGGL(fused_layer, dim3(8 * NN), dim3(512), 0, stream,
                     x, ste, g1, b1, g2, b2,
                     wq_t, bq, wk_t, bk, wv_t, bv,
                     wo1_t, bo1, wo2_t, bo2,
                     wf1_t, bf1, wf2_t, bf2, out);
}

// Round 13
// 524.014 us; speedup vs baseline: 1.2348x; 1.2348x over previous
//
#include <hip/hip_runtime.h>

#define TT 64
#define NN 512
#define DD 128

typedef __attribute__((ext_vector_type(8))) short bf16x8;
typedef __attribute__((ext_vector_type(4))) float f32x4;

__device__ __forceinline__ unsigned cvtpk(float lo, float hi) {
  unsigned r;
  asm("v_cvt_pk_bf16_f32 %0, %1, %2" : "=v"(r) : "v"(lo), "v"(hi));
  return r;
}

// XOR-swizzled LDS index helpers (units: unsigned short elements).
__device__ __forceinline__ int swz128(int row, int col) {
  return row * 128 + (((col >> 3) ^ (row & 15)) << 3) + (col & 7);
}
__device__ __forceinline__ int swz64(int row, int col) {
  return row * 64 + (((col >> 3) ^ (row & 7)) << 3) + (col & 7);
}

// Barrier with LDS-only drain: global loads stay in flight across it.
__device__ __forceinline__ void bar() {
  asm volatile("s_waitcnt lgkmcnt(0)" ::: "memory");
  __builtin_amdgcn_s_barrier();
  asm volatile("" ::: "memory");
}

// 16-lane (DPP-row) sum via row_ror butterflies — VALU pipe, no LDS traffic.
__device__ __forceinline__ float red16(float s) {
  int t;
  t = __builtin_amdgcn_update_dpp(0, __float_as_int(s), 0x121, 0xf, 0xf, false);
  s += __int_as_float(t);
  t = __builtin_amdgcn_update_dpp(0, __float_as_int(s), 0x122, 0xf, 0xf, false);
  s += __int_as_float(t);
  t = __builtin_amdgcn_update_dpp(0, __float_as_int(s), 0x124, 0xf, 0xf, false);
  s += __int_as_float(t);
  t = __builtin_amdgcn_update_dpp(0, __float_as_int(s), 0x128, 0xf, 0xf, false);
  s += __int_as_float(t);
  return s;
}

// transpose fp32 [K][N] -> bf16 [N][K]
__global__ void wprep(const float* __restrict__ src, unsigned short* __restrict__ dst,
                      int K, int Nn) {
  int idx = blockIdx.x * 256 + threadIdx.x;
  if (idx >= K * Nn) return;
  int n = idx / K, k = idx - n * K;
  float f = src[k * Nn + n];
  unsigned u = __float_as_uint(f);
  u += 0x7fffu + ((u >> 16) & 1u);
  dst[idx] = (unsigned short)(u >> 16);
}

#define KSCL 0.36067376022224085f   // 0.25 * log2(e), folded into K epilogue

// ============================ KERNEL A =====================================
// LN1 + col-strip QKV + wave-local causal attention -> AO (bf16) to global.
__global__ __launch_bounds__(512, 4)
void attn_head(const float* __restrict__ x_in, const float* __restrict__ ste,
               const float* __restrict__ g1, const float* __restrict__ b1,
               const unsigned short* __restrict__ wqt, const float* __restrict__ bq,
               const unsigned short* __restrict__ wkt, const float* __restrict__ bk,
               const unsigned short* __restrict__ wvt, const float* __restrict__ bv,
               unsigned short* __restrict__ aoG) {
  __shared__ __align__(16) unsigned short smem[32768];  // 64 KB

  const int tid = threadIdx.x;
  const int lane = tid & 63;
  const int w  = tid >> 6;         // wave 0..7
  const int lg = lane >> 4;        // 0..3
  const int li = lane & 15;
  const int hc = w * 16;           // col-strip base == head base

  const int blk = blockIdx.x;
  const int b = blk >> 9;          // N=512
  const int n = blk & 511;
  const int rs = NN * DD;
  const float* xbase = x_in + (b * TT * NN + n) * DD;
  const float* sbase = ste + (b * TT * NN + n) * DD;

  // Regions: X2s [0,16384) shorts; post-B0e overlays Qb [0,8192), AOb [8192,16384);
  // Kb [16384,24576), Vt [24576,32768) — written immediately (not overlays).
  unsigned short* X2s = smem;
  unsigned short* Qb  = smem;
  unsigned short* AOb = smem + 8192;
  unsigned short* Kb  = smem + 16384;
  unsigned short* Vt  = smem + 24576;

  #define SWZ256(row, col) ((row) * 256 + ((((col) >> 3) ^ ((row) & 15)) << 3) + ((col) & 7))

  // ---------------- LN1 + STE -> X2 (all input loads hoisted) --------------
  {
    const int t0 = w * 8 + lg;
    const float* xr0 = xbase + t0 * rs + li * 8;
    const float* xr1 = xbase + (t0 + 4) * rs + li * 8;
    const float* sr0 = sbase + t0 * rs + li * 8;
    const float* sr1 = sbase + (t0 + 4) * rs + li * 8;
    float4 xA0 = *(const float4*)(xr0);
    float4 xB0 = *(const float4*)(xr0 + 4);
    float4 xA1 = *(const float4*)(xr1);
    float4 xB1 = *(const float4*)(xr1 + 4);
    float4 sA0 = *(const float4*)(sr0);
    float4 sB0 = *(const float4*)(sr0 + 4);
    float4 sA1 = *(const float4*)(sr1);
    float4 sB1 = *(const float4*)(sr1 + 4);
    float4 gA = *(const float4*)(g1 + li * 8);
    float4 gB = *(const float4*)(g1 + li * 8 + 4);
    float4 bA = *(const float4*)(b1 + li * 8);
    float4 bB = *(const float4*)(b1 + li * 8 + 4);

    {  // row t0
      float s1 = xA0.x + xA0.y + xA0.z + xA0.w + xB0.x + xB0.y + xB0.z + xB0.w;
      float s2 = xA0.x * xA0.x + xA0.y * xA0.y + xA0.z * xA0.z + xA0.w * xA0.w +
                 xB0.x * xB0.x + xB0.y * xB0.y + xB0.z * xB0.z + xB0.w * xB0.w;
      s1 = red16(s1); s2 = red16(s2);
      float mean = s1 * (1.0f / 128.0f);
      float var = fmaxf((s2 - s1 * mean) * (1.0f / 127.0f), 0.0f);  // ddof=1
      float inv = 1.0f / (sqrtf(var) + 1e-6f);
      unsigned o01 = cvtpk(gA.x * (xA0.x - mean) * inv + bA.x, gA.y * (xA0.y - mean) * inv + bA.y);
      unsigned o23 = cvtpk(gA.z * (xA0.z - mean) * inv + bA.z, gA.w * (xA0.w - mean) * inv + bA.w);
      unsigned o45 = cvtpk(gB.x * (xB0.x - mean) * inv + bB.x, gB.y * (xB0.y - mean) * inv + bB.y);
      unsigned o67 = cvtpk(gB.z * (xB0.z - mean) * inv + bB.z, gB.w * (xB0.w - mean) * inv + bB.w);
      *(uint4*)(X2s + SWZ256(t0, li * 8)) = (uint4){o01, o23, o45, o67};
    }
    {  // row t0+4
      float s1 = xA1.x + xA1.y + xA1.z + xA1.w + xB1.x + xB1.y + xB1.z + xB1.w;
      float s2 = xA1.x * xA1.x + xA1.y * xA1.y + xA1.z * xA1.z + xA1.w * xA1.w +
                 xB1.x * xB1.x + xB1.y * xB1.y + xB1.z * xB1.z + xB1.w * xB1.w;
      s1 = red16(s1); s2 = red16(s2);
      float mean = s1 * (1.0f / 128.0f);
      float var = fmaxf((s2 - s1 * mean) * (1.0f / 127.0f), 0.0f);
      float inv = 1.0f / (sqrtf(var) + 1e-6f);
      unsigned o01 = cvtpk(gA.x * (xA1.x - mean) * inv + bA.x, gA.y * (xA1.y - mean) * inv + bA.y);
      unsigned o23 = cvtpk(gA.z * (xA1.z - mean) * inv + bA.z, gA.w * (xA1.w - mean) * inv + bA.w);
      unsigned o45 = cvtpk(gB.x * (xB1.x - mean) * inv + bB.x, gB.y * (xB1.y - mean) * inv + bB.y);
      unsigned o67 = cvtpk(gB.z * (xB1.z - mean) * inv + bB.z, gB.w * (xB1.w - mean) * inv + bB.w);
      *(uint4*)(X2s + SWZ256(t0 + 4, li * 8)) = (uint4){o01, o23, o45, o67};
    }
    *(uint4*)(X2s + SWZ256(t0, 128 + li * 8)) =
        (uint4){cvtpk(sA0.x, sA0.y), cvtpk(sA0.z, sA0.w), cvtpk(sB0.x, sB0.y), cvtpk(sB0.z, sB0.w)};
    *(uint4*)(X2s + SWZ256(t0 + 4, 128 + li * 8)) =
        (uint4){cvtpk(sA1.x, sA1.y), cvtpk(sA1.z, sA1.w), cvtpk(sB1.x, sB1.y), cvtpk(sB1.z, sB1.w)};
  }

  bar();  // B0: X2 visible

  // ---------------- V-pass (cols hc..hc+15), immediate epi -> Vt -----------
  {
    const unsigned short* vB = wvt + hc * 256;
    f32x4 va[4];
    #pragma unroll
    for (int rg = 0; rg < 4; ++rg) va[rg] = (f32x4){0, 0, 0, 0};
    #pragma unroll
    for (int kk = 0; kk < 8; ++kk) {
      bf16x8 bc = *(const bf16x8*)(vB + li * 256 + kk * 32 + lg * 8);
      #pragma unroll
      for (int rg = 0; rg < 4; ++rg) {
        bf16x8 af = *(const bf16x8*)(X2s + SWZ256(rg * 16 + li, kk * 32 + lg * 8));
        va[rg] = __builtin_amdgcn_mfma_f32_16x16x32_bf16(af, bc, va[rg], 0, 0, 0);
      }
    }
    float bvv = bv[hc + li];
    int d = hc + li;
    #pragma unroll
    for (int rg = 0; rg < 4; ++rg) {
      float v0 = fmaxf(va[rg][0] + bvv, 0.0f);
      float v1 = fmaxf(va[rg][1] + bvv, 0.0f);
      float v2 = fmaxf(va[rg][2] + bvv, 0.0f);
      float v3 = fmaxf(va[rg][3] + bvv, 0.0f);
      uint2 pv; pv.x = cvtpk(v0, v1); pv.y = cvtpk(v2, v3);
      *(uint2*)(Vt + swz64(d, rg * 16 + lg * 4)) = pv;
    }
  }

  // ---------------- K-pass (cols hc..hc+15), immediate epi -> Kb -----------
  {
    const unsigned short* kB = wkt + hc * 256;
    f32x4 ka[4];
    #pragma unroll
    for (int rg = 0; rg < 4; ++rg) ka[rg] = (f32x4){0, 0, 0, 0};
    #pragma unroll
    for (int kk = 0; kk < 8; ++kk) {
      bf16x8 bc = *(const bf16x8*)(kB + li * 256 + kk * 32 + lg * 8);
      #pragma unroll
      for (int rg = 0; rg < 4; ++rg) {
        bf16x8 af = *(const bf16x8*)(X2s + SWZ256(rg * 16 + li, kk * 32 + lg * 8));
        ka[rg] = __builtin_amdgcn_mfma_f32_16x16x32_bf16(af, bc, ka[rg], 0, 0, 0);
      }
    }
    float bkv = bk[hc + li];
    int col = hc + li;
    #pragma unroll
    for (int rg = 0; rg < 4; ++rg) {
      float k0 = fmaxf(ka[rg][0] + bkv, 0.0f) * KSCL;
      float k1 = fmaxf(ka[rg][1] + bkv, 0.0f) * KSCL;
      float k2 = fmaxf(ka[rg][2] + bkv, 0.0f) * KSCL;
      float k3 = fmaxf(ka[rg][3] + bkv, 0.0f) * KSCL;
      unsigned p01 = cvtpk(k0, k1), p23 = cvtpk(k2, k3);
      Kb[swz128(rg * 16 + lg * 4 + 0, col)] = (unsigned short)p01;
      Kb[swz128(rg * 16 + lg * 4 + 1, col)] = (unsigned short)(p01 >> 16);
      Kb[swz128(rg * 16 + lg * 4 + 2, col)] = (unsigned short)p23;
      Kb[swz128(rg * 16 + lg * 4 + 3, col)] = (unsigned short)(p23 >> 16);
    }
  }

  // ---------------- Q-pass (cols hc..hc+15) --------------------------------
  f32x4 qa[4];
  #pragma unroll
  for (int rg = 0; rg < 4; ++rg) qa[rg] = (f32x4){0, 0, 0, 0};
  {
    const unsigned short* qB = wqt + hc * 256;
    #pragma unroll
    for (int kk = 0; kk < 8; ++kk) {
      bf16x8 bc = *(const bf16x8*)(qB + li * 256 + kk * 32 + lg * 8);
      #pragma unroll
      for (int rg = 0; rg < 4; ++rg) {
        bf16x8 af = *(const bf16x8*)(X2s + SWZ256(rg * 16 + li, kk * 32 + lg * 8));
        qa[rg] = __builtin_amdgcn_mfma_f32_16x16x32_bf16(af, bc, qa[rg], 0, 0, 0);
      }
    }
  }

  bar();  // B0e: ALL X2 reads done -> Qb/AOb overlays live

  // Q epilogue -> Qb (own col strip; consumed only by this wave)
  {
    float bqv = bq[hc + li];
    int col = hc + li;
    #pragma unroll
    for (int rg = 0; rg < 4; ++rg) {
      float v0 = fmaxf(qa[rg][0] + bqv, 0.0f);
      float v1 = fmaxf(qa[rg][1] + bqv, 0.0f);
      float v2 = fmaxf(qa[rg][2] + bqv, 0.0f);
      float v3 = fmaxf(qa[rg][3] + bqv, 0.0f);
      unsigned p01 = cvtpk(v0, v1), p23 = cvtpk(v2, v3);
      Qb[swz128(rg * 16 + lg * 4 + 0, col)] = (unsigned short)p01;
      Qb[swz128(rg * 16 + lg * 4 + 1, col)] = (unsigned short)(p01 >> 16);
      Qb[swz128(rg * 16 + lg * 4 + 2, col)] = (unsigned short)p23;
      Qb[swz128(rg * 16 + lg * 4 + 3, col)] = (unsigned short)(p23 >> 16);
    }
  }

  // ---------------- causal attention, head w (all strips wave-local) -------
  {
    const bf16x8 zf = (bf16x8){0, 0, 0, 0, 0, 0, 0, 0};
    bf16x8 kf[4], vf[2];
    #pragma unroll
    for (int pt = 0; pt < 4; ++pt)
      kf[pt] = (lg < 2) ? *(const bf16x8*)(Kb + swz128(pt * 16 + li, hc + lg * 8)) : zf;
    #pragma unroll
    for (int ks = 0; ks < 2; ++ks)
      vf[ks] = *(const bf16x8*)(Vt + swz64(hc + li, ks * 32 + lg * 8));

    #pragma unroll
    for (int qt = 0; qt < 4; ++qt) {
      bf16x8 qf = (lg < 2) ? *(const bf16x8*)(Qb + swz128(qt * 16 + li, hc + lg * 8)) : zf;
      f32x4 st[4];
      #pragma unroll
      for (int pt = 0; pt < 4; ++pt)
        if (pt <= qt)
          st[pt] = __builtin_amdgcn_mfma_f32_16x16x32_bf16(kf[pt], qf, (f32x4){0, 0, 0, 0}, 0, 0, 0);

      float ssum = 0.0f;
      unsigned pa[4], pb[4];
      #pragma unroll
      for (int pt = 0; pt < 4; ++pt) {
        if (pt > qt) { pa[pt] = 0; pb[pt] = 0; continue; }
        float e0 = exp2f(st[pt][0]);
        float e1 = exp2f(st[pt][1]);
        float e2 = exp2f(st[pt][2]);
        float e3 = exp2f(st[pt][3]);
        if (pt == qt) {  // diagonal tile: mask p_local > q_local
          e0 = (4 * lg + 0 > li) ? 0.0f : e0;
          e1 = (4 * lg + 1 > li) ? 0.0f : e1;
          e2 = (4 * lg + 2 > li) ? 0.0f : e2;
          e3 = (4 * lg + 3 > li) ? 0.0f : e3;
        }
        ssum += e0 + e1 + e2 + e3;
        pa[pt] = cvtpk(e0, e1);
        pb[pt] = cvtpk(e2, e3);
      }
      ssum += __shfl_xor(ssum, 16, 64);
      ssum += __shfl_xor(ssum, 32, 64);
      float rinv = 1.0f / ssum;

      f32x4 oa = (f32x4){0, 0, 0, 0};
      #pragma unroll
      for (int ks = 0; ks < 2; ++ks) {
        if (ks * 2 > qt) continue;
        unsigned x = pa[2 * ks], y = pa[2 * ks + 1];
        asm("v_permlane32_swap_b32 %0, %1" : "+v"(x), "+v"(y));
        asm("v_permlane16_swap_b32 %0, %1" : "+v"(x), "+v"(y));
        unsigned u2 = pb[2 * ks], v2 = pb[2 * ks + 1];
        asm("v_permlane32_swap_b32 %0, %1" : "+v"(u2), "+v"(v2));
        asm("v_permlane16_swap_b32 %0, %1" : "+v"(u2), "+v"(v2));
        union { unsigned uw[4]; bf16x8 h; } pu;
        pu.uw[0] = x; pu.uw[1] = u2; pu.uw[2] = y; pu.uw[3] = v2;
        oa = __builtin_amdgcn_mfma_f32_16x16x32_bf16(vf[ks], pu.h, oa, 0, 0, 0);
      }
      uint2 ov;
      ov.x = cvtpk(oa[0] * rinv, oa[1] * rinv);
      ov.y = cvtpk(oa[2] * rinv, oa[3] * rinv);
      *(uint2*)(AOb + swz128(qt * 16 + li, hc + lg * 4)) = ov;
    }
  }

  bar();  // B2: AO strips visible

  // Coalesced AO store: wave w -> rows w*8..w*8+7, 16 lanes x 16B per row
  #pragma unroll
  for (int pass = 0; pass < 2; ++pass) {
    int t = w * 8 + pass * 4 + lg;
    uint4 v = *(const uint4*)(AOb + swz128(t, li * 8));
    *(uint4*)(aoG + ((b * TT + t) * NN + n) * DD + li * 8) = v;
  }
  #undef SWZ256
}

// ============================ KERNEL B =====================================
// Barrier-free tail: each wave owns 16 flat rows full-width.
// O1 -> O2 -> +x residual -> LN2 -> F1 -> F2 -> +residual -> out.
__device__ __forceinline__ void epi_sp8(const f32x4* acc, const float* __restrict__ bias,
                                        unsigned short* Sp, int li, int lg) {
  #pragma unroll
  for (int ct = 0; ct < 8; ++ct) {
    float bv = bias[ct * 16 + li];
    int col = ct * 16 + li;
    float v0 = fmaxf(acc[ct][0] + bv, 0.0f);
    float v1 = fmaxf(acc[ct][1] + bv, 0.0f);
    float v2 = fmaxf(acc[ct][2] + bv, 0.0f);
    float v3 = fmaxf(acc[ct][3] + bv, 0.0f);
    unsigned p01 = cvtpk(v0, v1), p23 = cvtpk(v2, v3);
    Sp[swz128(lg * 4 + 0, col)] = (unsigned short)p01;
    Sp[swz128(lg * 4 + 1, col)] = (unsigned short)(p01 >> 16);
    Sp[swz128(lg * 4 + 2, col)] = (unsigned short)p23;
    Sp[swz128(lg * 4 + 3, col)] = (unsigned short)(p23 >> 16);
  }
}

__global__ __launch_bounds__(256, 4)
void tail_ffn(const unsigned short* __restrict__ aoG, const float* __restrict__ x_in,
              const float* __restrict__ g2, const float* __restrict__ b2,
              const unsigned short* __restrict__ wo1t, const float* __restrict__ bo1,
              const unsigned short* __restrict__ wo2t, const float* __restrict__ bo2,
              const unsigned short* __restrict__ wf1t, const float* __restrict__ bf1,
              const unsigned short* __restrict__ wf2t, const float* __restrict__ bf2,
              float* __restrict__ out) {
  __shared__ __align__(16) unsigned short smem[8192];  // 16 KB: 4 x [16][128]
  const int tid = threadIdx.x;
  const int lane = tid & 63;
  const int w  = tid >> 6;          // wave 0..3
  const int lg = lane >> 4;
  const int li = lane & 15;
  unsigned short* Sp = smem + w * 2048;      // wave-private scratch
  const int R = blockIdx.x * 64 + w * 16;    // flat row base (b*T*N rows total)

  // O1: A-frags straight from global AO
  bf16x8 af4[4];
  #pragma unroll
  for (int kk = 0; kk < 4; ++kk)
    af4[kk] = *(const bf16x8*)(aoG + (R + li) * DD + kk * 32 + lg * 8);
  f32x4 a1[8];
  #pragma unroll
  for (int i = 0; i < 8; ++i) a1[i] = (f32x4){0, 0, 0, 0};
  #pragma unroll
  for (int kk = 0; kk < 4; ++kk)
    #pragma unroll
    for (int ct = 0; ct < 8; ++ct)
      a1[ct] = __builtin_amdgcn_mfma_f32_16x16x32_bf16(
          af4[kk], *(const bf16x8*)(wo1t + (ct * 16 + li) * 128 + kk * 32 + lg * 8),
          a1[ct], 0, 0, 0);
  epi_sp8(a1, bo1, Sp, li, lg);

  // O2 (H1 from private Sp; same-wave DS in-order)
  #pragma unroll
  for (int kk = 0; kk < 4; ++kk)
    af4[kk] = *(const bf16x8*)(Sp + swz128(li, kk * 32 + lg * 8));
  f32x4 ya[8];
  #pragma unroll
  for (int i = 0; i < 8; ++i) ya[i] = (f32x4){0, 0, 0, 0};
  #pragma unroll
  for (int kk = 0; kk < 4; ++kk)
    #pragma unroll
    for (int ct = 0; ct < 8; ++ct)
      ya[ct] = __builtin_amdgcn_mfma_f32_16x16x32_bf16(
          af4[kk], *(const bf16x8*)(wo2t + (ct * 16 + li) * 128 + kk * 32 + lg * 8),
          ya[ct], 0, 0, 0);

  // residual + LN2 (wave-local)
  float x2r[8][4];
  #pragma unroll
  for (int ct = 0; ct < 8; ++ct) {
    float bvv = bo2[ct * 16 + li];
    #pragma unroll
    for (int r = 0; r < 4; ++r)
      x2r[ct][r] = ya[ct][r] + bvv + x_in[(R + lg * 4 + r) * DD + ct * 16 + li];
  }
  float s1p[4] = {0, 0, 0, 0}, s2p[4] = {0, 0, 0, 0};
  #pragma unroll
  for (int ct = 0; ct < 8; ++ct)
    #pragma unroll
    for (int r = 0; r < 4; ++r) {
      float v = x2r[ct][r];
      s1p[r] += v; s2p[r] += v * v;
    }
  float mean_[4], inv_[4];
  #pragma unroll
  for (int r = 0; r < 4; ++r) {
    float s1 = red16(s1p[r]);
    float s2 = red16(s2p[r]);
    float mean = s1 * (1.0f / 128.0f);
    float var = fmaxf((s2 - s1 * mean) * (1.0f / 127.0f), 0.0f);  // ddof=1
    mean_[r] = mean;
    inv_[r] = 1.0f / (sqrtf(var) + 1e-6f);
  }
  #pragma unroll
  for (int ct = 0; ct < 8; ++ct) {  // Xn2 -> private Sp
    int col = ct * 16 + li;
    float gv = g2[col], bv2 = b2[col];
    float xn0 = gv * (x2r[ct][0] - mean_[0]) * inv_[0] + bv2;
    float xn1 = gv * (x2r[ct][1] - mean_[1]) * inv_[1] + bv2;
    float xn2 = gv * (x2r[ct][2] - mean_[2]) * inv_[2] + bv2;
    float xn3 = gv * (x2r[ct][3] - mean_[3]) * inv_[3] + bv2;
    unsigned p01 = cvtpk(xn0, xn1), p23 = cvtpk(xn2, xn3);
    Sp[swz128(lg * 4 + 0, col)] = (unsigned short)p01;
    Sp[swz128(lg * 4 + 1, col)] = (unsigned short)(p01 >> 16);
    Sp[swz128(lg * 4 + 2, col)] = (unsigned short)p23;
    Sp[swz128(lg * 4 + 3, col)] = (unsigned short)(p23 >> 16);
  }

  // F1
  #pragma unroll
  for (int kk = 0; kk < 4; ++kk)
    af4[kk] = *(const bf16x8*)(Sp + swz128(li, kk * 32 + lg * 8));
  f32x4 f1a[8];
  #pragma unroll
  for (int i = 0; i < 8; ++i) f1a[i] = (f32x4){0, 0, 0, 0};
  #pragma unroll
  for (int kk = 0; kk < 4; ++kk)
    #pragma unroll
    for (int ct = 0; ct < 8; ++ct)
      f1a[ct] = __builtin_amdgcn_mfma_f32_16x16x32_bf16(
          af4[kk], *(const bf16x8*)(wf1t + (ct * 16 + li) * 128 + kk * 32 + lg * 8),
          f1a[ct], 0, 0, 0);
  epi_sp8(f1a, bf1, Sp, li, lg);

  // F2 + final residual
  #pragma unroll
  for (int kk = 0; kk < 4; ++kk)
    af4[kk] = *(const bf16x8*)(Sp + swz128(li, kk * 32 + lg * 8));
  f32x4 f2a[8];
  #pragma unroll
  for (int i = 0; i < 8; ++i) f2a[i] = (f32x4){0, 0, 0, 0};
  #pragma unroll
  for (int kk = 0; kk < 4; ++kk)
    #pragma unroll
    for (int ct = 0; ct < 8; ++ct)
      f2a[ct] = __builtin_amdgcn_mfma_f32_16x16x32_bf16(
          af4[kk], *(const bf16x8*)(wf2t + (ct * 16 + li) * 128 + kk * 32 + lg * 8),
          f2a[ct], 0, 0, 0);

  #pragma unroll
  for (int ct = 0; ct < 8; ++ct) {
    float bvv = bf2[ct * 16 + li];
    #pragma unroll
    for (int r = 0; r < 4; ++r)
      out[(R + lg * 4 + r) * DD + ct * 16 + li] =
          x2r[ct][r] + fmaxf(f2a[ct][r] + bvv, 0.0f);
  }
}

extern "C" void kernel_launch(void* const* d_in, const int* in_sizes, int n_in,
                              void* d_out, int out_size, void* d_ws, size_t ws_size,
                              hipStream_t stream) {
  const float* x   = (const float*)d_in[0];
  const float* ste = (const float*)d_in[1];
  const float* g1 = (const float*)d_in[3];
  const float* b1 = (const float*)d_in[4];
  const float* g2 = (const float*)d_in[5];
  const float* b2 = (const float*)d_in[6];
  const float* Wq = (const float*)d_in[7];   const float* bq  = (const float*)d_in[8];
  const float* Wk = (const float*)d_in[9];   const float* bk  = (const float*)d_in[10];
  const float* Wv = (const float*)d_in[11];  const float* bv  = (const float*)d_in[12];
  const float* Wo1 = (const float*)d_in[13]; const float* bo1 = (const float*)d_in[14];
  const float* Wo2 = (const float*)d_in[15]; const float* bo2 = (const float*)d_in[16];
  const float* Wf1 = (const float*)d_in[17]; const float* bf1 = (const float*)d_in[18];
  const float* Wf2 = (const float*)d_in[19]; const float* bf2 = (const float*)d_in[20];
  float* out = (float*)d_out;

  unsigned short* wsu = (unsigned short*)d_ws;
  unsigned short* wq_t  = wsu;             // [128][256]
  unsigned short* wk_t  = wsu + 32768;
  unsigned short* wv_t  = wsu + 65536;
  unsigned short* wo1_t = wsu + 98304;     // [128][128]
  unsigned short* wo2_t = wsu + 114688;
  unsigned short* wf1_t = wsu + 131072;
  unsigned short* wf2_t = wsu + 147456;
  unsigned short* ao    = wsu + 163840;    // [B*T*N][128] bf16 = 64 MB

  hipLaunchKernelGGL(wprep, dim3(128), dim3(256), 0, stream, Wq, wq_t, 256, 128);
  hipLaunchKernelGGL(wprep, dim3(128), dim3(256), 0, stream, Wk, wk_t, 256, 128);
  hipLaunchKernelGGL(wprep, dim3(128), dim3(256), 0, stream, Wv, wv_t, 256, 128);
  hipLaunchKernelGGL(wprep, dim3(64), dim3(256), 0, stream, Wo1, wo1_t, 128, 128);
  hipLaunchKernelGGL(wprep, dim3(64), dim3(256), 0, stream, Wo2, wo2_t, 128, 128);
  hipLaunchKernelGGL(wprep, dim3(64), dim3(256), 0, stream, Wf1, wf1_t, 128, 128);
  hipLaunchKernelGGL(wprep, dim3(64), dim3(256), 0, stream, Wf2, wf2_t, 128, 128);

  hipLaunchKernelGGL(attn_head, dim3(8 * NN), dim3(512), 0, stream,
                     x, ste, g1, b1, wq_t, bq, wk_t, bk, wv_t, bv, ao);
  hipLaunchKernelGGL(tail_ffn, dim3(8 * TT * NN / 64), dim3(256), 0, stream,
                     ao, x, g2, b2, wo1_t, bo1, wo2_t, bo2,
                     wf1_t, bf1, wf2_t, bf2, out);
}

// Round 14
// 478.329 us; speedup vs baseline: 1.3528x; 1.0955x over previous
//
#include <hip/hip_runtime.h>

#define TT 64
#define NN 512
#define DD 128

typedef __attribute__((ext_vector_type(8))) short bf16x8;
typedef __attribute__((ext_vector_type(4))) float f32x4;

__device__ __forceinline__ unsigned cvtpk(float lo, float hi) {
  unsigned r;
  asm("v_cvt_pk_bf16_f32 %0, %1, %2" : "=v"(r) : "v"(lo), "v"(hi));
  return r;
}

// XOR-swizzled LDS index helpers (units: unsigned short elements).
__device__ __forceinline__ int swz128(int row, int col) {
  return row * 128 + (((col >> 3) ^ (row & 15)) << 3) + (col & 7);
}
__device__ __forceinline__ int swz64(int row, int col) {
  return row * 64 + (((col >> 3) ^ (row & 7)) << 3) + (col & 7);
}

// Barrier with LDS-only drain: global loads stay in flight across it.
__device__ __forceinline__ void bar() {
  asm volatile("s_waitcnt lgkmcnt(0)" ::: "memory");
  __builtin_amdgcn_s_barrier();
  asm volatile("" ::: "memory");
}

// 16-lane (DPP-row) sum via row_ror butterflies — VALU pipe, no LDS traffic.
__device__ __forceinline__ float red16(float s) {
  int t;
  t = __builtin_amdgcn_update_dpp(0, __float_as_int(s), 0x121, 0xf, 0xf, false);
  s += __int_as_float(t);
  t = __builtin_amdgcn_update_dpp(0, __float_as_int(s), 0x122, 0xf, 0xf, false);
  s += __int_as_float(t);
  t = __builtin_amdgcn_update_dpp(0, __float_as_int(s), 0x124, 0xf, 0xf, false);
  s += __int_as_float(t);
  t = __builtin_amdgcn_update_dpp(0, __float_as_int(s), 0x128, 0xf, 0xf, false);
  s += __int_as_float(t);
  return s;
}

// transpose fp32 [K][N] -> bf16 [N][K]
__global__ void wprep(const float* __restrict__ src, unsigned short* __restrict__ dst,
                      int K, int Nn) {
  int idx = blockIdx.x * 256 + threadIdx.x;
  if (idx >= K * Nn) return;
  int n = idx / K, k = idx - n * K;
  float f = src[k * Nn + n];
  unsigned u = __float_as_uint(f);
  u += 0x7fffu + ((u >> 16) & 1u);
  dst[idx] = (unsigned short)(u >> 16);
}

#define KSCL 0.36067376022224085f   // 0.25 * log2(e), folded into K epilogue

// ============================ KERNEL A =====================================
// LN1 + col-strip QKV + wave-local causal attention -> AO (bf16) to global.
__global__ __launch_bounds__(512, 4)
void attn_head(const float* __restrict__ x_in, const float* __restrict__ ste,
               const float* __restrict__ g1, const float* __restrict__ b1,
               const unsigned short* __restrict__ wqt, const float* __restrict__ bq,
               const unsigned short* __restrict__ wkt, const float* __restrict__ bk,
               const unsigned short* __restrict__ wvt, const float* __restrict__ bv,
               unsigned short* __restrict__ aoG) {
  __shared__ __align__(16) unsigned short smem[32768];  // 64 KB

  const int tid = threadIdx.x;
  const int lane = tid & 63;
  const int w  = tid >> 6;         // wave 0..7
  const int lg = lane >> 4;        // 0..3
  const int li = lane & 15;
  const int hc = w * 16;           // col-strip base == head base

  const int blk = blockIdx.x;
  const int b = blk >> 9;          // N=512
  const int n = blk & 511;
  const int rs = NN * DD;
  const float* xbase = x_in + (b * TT * NN + n) * DD;
  const float* sbase = ste + (b * TT * NN + n) * DD;

  unsigned short* X2s = smem;
  unsigned short* Qb  = smem;
  unsigned short* AOb = smem + 8192;
  unsigned short* Kb  = smem + 16384;
  unsigned short* Vt  = smem + 24576;

  #define SWZ256(row, col) ((row) * 256 + ((((col) >> 3) ^ ((row) & 15)) << 3) + ((col) & 7))

  // ---------------- LN1 + STE -> X2 (all input loads hoisted) --------------
  {
    const int t0 = w * 8 + lg;
    const float* xr0 = xbase + t0 * rs + li * 8;
    const float* xr1 = xbase + (t0 + 4) * rs + li * 8;
    const float* sr0 = sbase + t0 * rs + li * 8;
    const float* sr1 = sbase + (t0 + 4) * rs + li * 8;
    float4 xA0 = *(const float4*)(xr0);
    float4 xB0 = *(const float4*)(xr0 + 4);
    float4 xA1 = *(const float4*)(xr1);
    float4 xB1 = *(const float4*)(xr1 + 4);
    float4 sA0 = *(const float4*)(sr0);
    float4 sB0 = *(const float4*)(sr0 + 4);
    float4 sA1 = *(const float4*)(sr1);
    float4 sB1 = *(const float4*)(sr1 + 4);
    float4 gA = *(const float4*)(g1 + li * 8);
    float4 gB = *(const float4*)(g1 + li * 8 + 4);
    float4 bA = *(const float4*)(b1 + li * 8);
    float4 bB = *(const float4*)(b1 + li * 8 + 4);

    {  // row t0
      float s1 = xA0.x + xA0.y + xA0.z + xA0.w + xB0.x + xB0.y + xB0.z + xB0.w;
      float s2 = xA0.x * xA0.x + xA0.y * xA0.y + xA0.z * xA0.z + xA0.w * xA0.w +
                 xB0.x * xB0.x + xB0.y * xB0.y + xB0.z * xB0.z + xB0.w * xB0.w;
      s1 = red16(s1); s2 = red16(s2);
      float mean = s1 * (1.0f / 128.0f);
      float var = fmaxf((s2 - s1 * mean) * (1.0f / 127.0f), 0.0f);  // ddof=1
      float inv = 1.0f / (sqrtf(var) + 1e-6f);
      unsigned o01 = cvtpk(gA.x * (xA0.x - mean) * inv + bA.x, gA.y * (xA0.y - mean) * inv + bA.y);
      unsigned o23 = cvtpk(gA.z * (xA0.z - mean) * inv + bA.z, gA.w * (xA0.w - mean) * inv + bA.w);
      unsigned o45 = cvtpk(gB.x * (xB0.x - mean) * inv + bB.x, gB.y * (xB0.y - mean) * inv + bB.y);
      unsigned o67 = cvtpk(gB.z * (xB0.z - mean) * inv + bB.z, gB.w * (xB0.w - mean) * inv + bB.w);
      *(uint4*)(X2s + SWZ256(t0, li * 8)) = (uint4){o01, o23, o45, o67};
    }
    {  // row t0+4
      float s1 = xA1.x + xA1.y + xA1.z + xA1.w + xB1.x + xB1.y + xB1.z + xB1.w;
      float s2 = xA1.x * xA1.x + xA1.y * xA1.y + xA1.z * xA1.z + xA1.w * xA1.w +
                 xB1.x * xB1.x + xB1.y * xB1.y + xB1.z * xB1.z + xB1.w * xB1.w;
      s1 = red16(s1); s2 = red16(s2);
      float mean = s1 * (1.0f / 128.0f);
      float var = fmaxf((s2 - s1 * mean) * (1.0f / 127.0f), 0.0f);
      float inv = 1.0f / (sqrtf(var) + 1e-6f);
      unsigned o01 = cvtpk(gA.x * (xA1.x - mean) * inv + bA.x, gA.y * (xA1.y - mean) * inv + bA.y);
      unsigned o23 = cvtpk(gA.z * (xA1.z - mean) * inv + bA.z, gA.w * (xA1.w - mean) * inv + bA.w);
      unsigned o45 = cvtpk(gB.x * (xB1.x - mean) * inv + bB.x, gB.y * (xB1.y - mean) * inv + bB.y);
      unsigned o67 = cvtpk(gB.z * (xB1.z - mean) * inv + bB.z, gB.w * (xB1.w - mean) * inv + bB.w);
      *(uint4*)(X2s + SWZ256(t0 + 4, li * 8)) = (uint4){o01, o23, o45, o67};
    }
    *(uint4*)(X2s + SWZ256(t0, 128 + li * 8)) =
        (uint4){cvtpk(sA0.x, sA0.y), cvtpk(sA0.z, sA0.w), cvtpk(sB0.x, sB0.y), cvtpk(sB0.z, sB0.w)};
    *(uint4*)(X2s + SWZ256(t0 + 4, 128 + li * 8)) =
        (uint4){cvtpk(sA1.x, sA1.y), cvtpk(sA1.z, sA1.w), cvtpk(sB1.x, sB1.y), cvtpk(sB1.z, sB1.w)};
  }

  bar();  // B0: X2 visible

  // ---------------- V-pass (cols hc..hc+15), immediate epi -> Vt -----------
  {
    const unsigned short* vB = wvt + hc * 256;
    f32x4 va[4];
    #pragma unroll
    for (int rg = 0; rg < 4; ++rg) va[rg] = (f32x4){0, 0, 0, 0};
    #pragma unroll
    for (int kk = 0; kk < 8; ++kk) {
      bf16x8 bc = *(const bf16x8*)(vB + li * 256 + kk * 32 + lg * 8);
      #pragma unroll
      for (int rg = 0; rg < 4; ++rg) {
        bf16x8 af = *(const bf16x8*)(X2s + SWZ256(rg * 16 + li, kk * 32 + lg * 8));
        va[rg] = __builtin_amdgcn_mfma_f32_16x16x32_bf16(af, bc, va[rg], 0, 0, 0);
      }
    }
    float bvv = bv[hc + li];
    int d = hc + li;
    #pragma unroll
    for (int rg = 0; rg < 4; ++rg) {
      float v0 = fmaxf(va[rg][0] + bvv, 0.0f);
      float v1 = fmaxf(va[rg][1] + bvv, 0.0f);
      float v2 = fmaxf(va[rg][2] + bvv, 0.0f);
      float v3 = fmaxf(va[rg][3] + bvv, 0.0f);
      uint2 pv; pv.x = cvtpk(v0, v1); pv.y = cvtpk(v2, v3);
      *(uint2*)(Vt + swz64(d, rg * 16 + lg * 4)) = pv;
    }
  }

  // ---------------- K-pass (cols hc..hc+15), immediate epi -> Kb -----------
  {
    const unsigned short* kB = wkt + hc * 256;
    f32x4 ka[4];
    #pragma unroll
    for (int rg = 0; rg < 4; ++rg) ka[rg] = (f32x4){0, 0, 0, 0};
    #pragma unroll
    for (int kk = 0; kk < 8; ++kk) {
      bf16x8 bc = *(const bf16x8*)(kB + li * 256 + kk * 32 + lg * 8);
      #pragma unroll
      for (int rg = 0; rg < 4; ++rg) {
        bf16x8 af = *(const bf16x8*)(X2s + SWZ256(rg * 16 + li, kk * 32 + lg * 8));
        ka[rg] = __builtin_amdgcn_mfma_f32_16x16x32_bf16(af, bc, ka[rg], 0, 0, 0);
      }
    }
    float bkv = bk[hc + li];
    int col = hc + li;
    #pragma unroll
    for (int rg = 0; rg < 4; ++rg) {
      float k0 = fmaxf(ka[rg][0] + bkv, 0.0f) * KSCL;
      float k1 = fmaxf(ka[rg][1] + bkv, 0.0f) * KSCL;
      float k2 = fmaxf(ka[rg][2] + bkv, 0.0f) * KSCL;
      float k3 = fmaxf(ka[rg][3] + bkv, 0.0f) * KSCL;
      unsigned p01 = cvtpk(k0, k1), p23 = cvtpk(k2, k3);
      Kb[swz128(rg * 16 + lg * 4 + 0, col)] = (unsigned short)p01;
      Kb[swz128(rg * 16 + lg * 4 + 1, col)] = (unsigned short)(p01 >> 16);
      Kb[swz128(rg * 16 + lg * 4 + 2, col)] = (unsigned short)p23;
      Kb[swz128(rg * 16 + lg * 4 + 3, col)] = (unsigned short)(p23 >> 16);
    }
  }

  // ---------------- Q-pass (cols hc..hc+15) --------------------------------
  f32x4 qa[4];
  #pragma unroll
  for (int rg = 0; rg < 4; ++rg) qa[rg] = (f32x4){0, 0, 0, 0};
  {
    const unsigned short* qB = wqt + hc * 256;
    #pragma unroll
    for (int kk = 0; kk < 8; ++kk) {
      bf16x8 bc = *(const bf16x8*)(qB + li * 256 + kk * 32 + lg * 8);
      #pragma unroll
      for (int rg = 0; rg < 4; ++rg) {
        bf16x8 af = *(const bf16x8*)(X2s + SWZ256(rg * 16 + li, kk * 32 + lg * 8));
        qa[rg] = __builtin_amdgcn_mfma_f32_16x16x32_bf16(af, bc, qa[rg], 0, 0, 0);
      }
    }
  }

  bar();  // B0e: ALL X2 reads done -> Qb/AOb overlays live

  // Q epilogue -> Qb (own col strip; consumed only by this wave)
  {
    float bqv = bq[hc + li];
    int col = hc + li;
    #pragma unroll
    for (int rg = 0; rg < 4; ++rg) {
      float v0 = fmaxf(qa[rg][0] + bqv, 0.0f);
      float v1 = fmaxf(qa[rg][1] + bqv, 0.0f);
      float v2 = fmaxf(qa[rg][2] + bqv, 0.0f);
      float v3 = fmaxf(qa[rg][3] + bqv, 0.0f);
      unsigned p01 = cvtpk(v0, v1), p23 = cvtpk(v2, v3);
      Qb[swz128(rg * 16 + lg * 4 + 0, col)] = (unsigned short)p01;
      Qb[swz128(rg * 16 + lg * 4 + 1, col)] = (unsigned short)(p01 >> 16);
      Qb[swz128(rg * 16 + lg * 4 + 2, col)] = (unsigned short)p23;
      Qb[swz128(rg * 16 + lg * 4 + 3, col)] = (unsigned short)(p23 >> 16);
    }
  }

  // ---------------- causal attention, head w (all strips wave-local) -------
  {
    const bf16x8 zf = (bf16x8){0, 0, 0, 0, 0, 0, 0, 0};
    bf16x8 kf[4], vf[2];
    #pragma unroll
    for (int pt = 0; pt < 4; ++pt)
      kf[pt] = (lg < 2) ? *(const bf16x8*)(Kb + swz128(pt * 16 + li, hc + lg * 8)) : zf;
    #pragma unroll
    for (int ks = 0; ks < 2; ++ks)
      vf[ks] = *(const bf16x8*)(Vt + swz64(hc + li, ks * 32 + lg * 8));

    #pragma unroll
    for (int qt = 0; qt < 4; ++qt) {
      bf16x8 qf = (lg < 2) ? *(const bf16x8*)(Qb + swz128(qt * 16 + li, hc + lg * 8)) : zf;
      f32x4 st[4];
      #pragma unroll
      for (int pt = 0; pt < 4; ++pt)
        if (pt <= qt)
          st[pt] = __builtin_amdgcn_mfma_f32_16x16x32_bf16(kf[pt], qf, (f32x4){0, 0, 0, 0}, 0, 0, 0);

      float ssum = 0.0f;
      unsigned pa[4], pb[4];
      #pragma unroll
      for (int pt = 0; pt < 4; ++pt) {
        if (pt > qt) { pa[pt] = 0; pb[pt] = 0; continue; }
        float e0 = exp2f(st[pt][0]);
        float e1 = exp2f(st[pt][1]);
        float e2 = exp2f(st[pt][2]);
        float e3 = exp2f(st[pt][3]);
        if (pt == qt) {  // diagonal tile: mask p_local > q_local
          e0 = (4 * lg + 0 > li) ? 0.0f : e0;
          e1 = (4 * lg + 1 > li) ? 0.0f : e1;
          e2 = (4 * lg + 2 > li) ? 0.0f : e2;
          e3 = (4 * lg + 3 > li) ? 0.0f : e3;
        }
        ssum += e0 + e1 + e2 + e3;
        pa[pt] = cvtpk(e0, e1);
        pb[pt] = cvtpk(e2, e3);
      }
      ssum += __shfl_xor(ssum, 16, 64);
      ssum += __shfl_xor(ssum, 32, 64);
      float rinv = 1.0f / ssum;

      f32x4 oa = (f32x4){0, 0, 0, 0};
      #pragma unroll
      for (int ks = 0; ks < 2; ++ks) {
        if (ks * 2 > qt) continue;
        unsigned x = pa[2 * ks], y = pa[2 * ks + 1];
        asm("v_permlane32_swap_b32 %0, %1" : "+v"(x), "+v"(y));
        asm("v_permlane16_swap_b32 %0, %1" : "+v"(x), "+v"(y));
        unsigned u2 = pb[2 * ks], v2 = pb[2 * ks + 1];
        asm("v_permlane32_swap_b32 %0, %1" : "+v"(u2), "+v"(v2));
        asm("v_permlane16_swap_b32 %0, %1" : "+v"(u2), "+v"(v2));
        union { unsigned uw[4]; bf16x8 h; } pu;
        pu.uw[0] = x; pu.uw[1] = u2; pu.uw[2] = y; pu.uw[3] = v2;
        oa = __builtin_amdgcn_mfma_f32_16x16x32_bf16(vf[ks], pu.h, oa, 0, 0, 0);
      }
      uint2 ov;
      ov.x = cvtpk(oa[0] * rinv, oa[1] * rinv);
      ov.y = cvtpk(oa[2] * rinv, oa[3] * rinv);
      *(uint2*)(AOb + swz128(qt * 16 + li, hc + lg * 4)) = ov;
    }
  }

  bar();  // B2: AO strips visible

  // Coalesced AO store: wave w -> rows w*8..w*8+7, 16 lanes x 16B per row
  #pragma unroll
  for (int pass = 0; pass < 2; ++pass) {
    int t = w * 8 + pass * 4 + lg;
    uint4 v = *(const uint4*)(AOb + swz128(t, li * 8));
    *(uint4*)(aoG + ((b * TT + t) * NN + n) * DD + li * 8) = v;
  }
  #undef SWZ256
}

// ============================ KERNEL B =====================================
// Barrier-free tail: each wave owns 16 flat rows full-width.
// amdgpu_waves_per_eu(4,4): stop the allocator from chasing 8 waves/EU with
// 64 regs + 38 spill slots (R13: 160 MB of scratch stores). 128-reg budget.
__device__ __forceinline__ void epi_sp8(const f32x4* acc, const float* __restrict__ bias,
                                        unsigned short* Sp, int li, int lg) {
  #pragma unroll
  for (int ct = 0; ct < 8; ++ct) {
    float bv = bias[ct * 16 + li];
    int col = ct * 16 + li;
    float v0 = fmaxf(acc[ct][0] + bv, 0.0f);
    float v1 = fmaxf(acc[ct][1] + bv, 0.0f);
    float v2 = fmaxf(acc[ct][2] + bv, 0.0f);
    float v3 = fmaxf(acc[ct][3] + bv, 0.0f);
    unsigned p01 = cvtpk(v0, v1), p23 = cvtpk(v2, v3);
    Sp[swz128(lg * 4 + 0, col)] = (unsigned short)p01;
    Sp[swz128(lg * 4 + 1, col)] = (unsigned short)(p01 >> 16);
    Sp[swz128(lg * 4 + 2, col)] = (unsigned short)p23;
    Sp[swz128(lg * 4 + 3, col)] = (unsigned short)(p23 >> 16);
  }
}

__global__ __launch_bounds__(256)
__attribute__((amdgpu_waves_per_eu(4, 4)))
void tail_ffn(const unsigned short* __restrict__ aoG, const float* __restrict__ x_in,
              const float* __restrict__ g2, const float* __restrict__ b2,
              const unsigned short* __restrict__ wo1t, const float* __restrict__ bo1,
              const unsigned short* __restrict__ wo2t, const float* __restrict__ bo2,
              const unsigned short* __restrict__ wf1t, const float* __restrict__ bf1,
              const unsigned short* __restrict__ wf2t, const float* __restrict__ bf2,
              float* __restrict__ out) {
  __shared__ __align__(16) unsigned short smem[8192];  // 16 KB: 4 x [16][128]
  const int tid = threadIdx.x;
  const int lane = tid & 63;
  const int w  = tid >> 6;          // wave 0..3
  const int lg = lane >> 4;
  const int li = lane & 15;
  unsigned short* Sp = smem + w * 2048;      // wave-private scratch
  const int R = blockIdx.x * 64 + w * 16;    // flat row base (b*T*N rows total)

  // residual x loads issued FIRST: ~2 GEMM stages of latency hiding
  float xr[8][4];
  #pragma unroll
  for (int ct = 0; ct < 8; ++ct)
    #pragma unroll
    for (int r = 0; r < 4; ++r)
      xr[ct][r] = x_in[(R + lg * 4 + r) * DD + ct * 16 + li];

  // O1: A-frags straight from global AO
  bf16x8 af4[4];
  #pragma unroll
  for (int kk = 0; kk < 4; ++kk)
    af4[kk] = *(const bf16x8*)(aoG + (R + li) * DD + kk * 32 + lg * 8);
  f32x4 a1[8];
  #pragma unroll
  for (int i = 0; i < 8; ++i) a1[i] = (f32x4){0, 0, 0, 0};
  #pragma unroll
  for (int kk = 0; kk < 4; ++kk)
    #pragma unroll
    for (int ct = 0; ct < 8; ++ct)
      a1[ct] = __builtin_amdgcn_mfma_f32_16x16x32_bf16(
          af4[kk], *(const bf16x8*)(wo1t + (ct * 16 + li) * 128 + kk * 32 + lg * 8),
          a1[ct], 0, 0, 0);
  epi_sp8(a1, bo1, Sp, li, lg);

  // O2 (H1 from private Sp; same-wave DS in-order)
  #pragma unroll
  for (int kk = 0; kk < 4; ++kk)
    af4[kk] = *(const bf16x8*)(Sp + swz128(li, kk * 32 + lg * 8));
  f32x4 ya[8];
  #pragma unroll
  for (int i = 0; i < 8; ++i) ya[i] = (f32x4){0, 0, 0, 0};
  #pragma unroll
  for (int kk = 0; kk < 4; ++kk)
    #pragma unroll
    for (int ct = 0; ct < 8; ++ct)
      ya[ct] = __builtin_amdgcn_mfma_f32_16x16x32_bf16(
          af4[kk], *(const bf16x8*)(wo2t + (ct * 16 + li) * 128 + kk * 32 + lg * 8),
          ya[ct], 0, 0, 0);

  // residual + LN2 (wave-local)
  float x2r[8][4];
  #pragma unroll
  for (int ct = 0; ct < 8; ++ct) {
    float bvv = bo2[ct * 16 + li];
    #pragma unroll
    for (int r = 0; r < 4; ++r)
      x2r[ct][r] = ya[ct][r] + bvv + xr[ct][r];
  }
  float s1p[4] = {0, 0, 0, 0}, s2p[4] = {0, 0, 0, 0};
  #pragma unroll
  for (int ct = 0; ct < 8; ++ct)
    #pragma unroll
    for (int r = 0; r < 4; ++r) {
      float v = x2r[ct][r];
      s1p[r] += v; s2p[r] += v * v;
    }
  float mean_[4], inv_[4];
  #pragma unroll
  for (int r = 0; r < 4; ++r) {
    float s1 = red16(s1p[r]);
    float s2 = red16(s2p[r]);
    float mean = s1 * (1.0f / 128.0f);
    float var = fmaxf((s2 - s1 * mean) * (1.0f / 127.0f), 0.0f);  // ddof=1
    mean_[r] = mean;
    inv_[r] = 1.0f / (sqrtf(var) + 1e-6f);
  }
  #pragma unroll
  for (int ct = 0; ct < 8; ++ct) {  // Xn2 -> private Sp
    int col = ct * 16 + li;
    float gv = g2[col], bv2 = b2[col];
    float xn0 = gv * (x2r[ct][0] - mean_[0]) * inv_[0] + bv2;
    float xn1 = gv * (x2r[ct][1] - mean_[1]) * inv_[1] + bv2;
    float xn2 = gv * (x2r[ct][2] - mean_[2]) * inv_[2] + bv2;
    float xn3 = gv * (x2r[ct][3] - mean_[3]) * inv_[3] + bv2;
    unsigned p01 = cvtpk(xn0, xn1), p23 = cvtpk(xn2, xn3);
    Sp[swz128(lg * 4 + 0, col)] = (unsigned short)p01;
    Sp[swz128(lg * 4 + 1, col)] = (unsigned short)(p01 >> 16);
    Sp[swz128(lg * 4 + 2, col)] = (unsigned short)p23;
    Sp[swz128(lg * 4 + 3, col)] = (unsigned short)(p23 >> 16);
  }

  // F1
  #pragma unroll
  for (int kk = 0; kk < 4; ++kk)
    af4[kk] = *(const bf16x8*)(Sp + swz128(li, kk * 32 + lg * 8));
  f32x4 f1a[8];
  #pragma unroll
  for (int i = 0; i < 8; ++i) f1a[i] = (f32x4){0, 0, 0, 0};
  #pragma unroll
  for (int kk = 0; kk < 4; ++kk)
    #pragma unroll
    for (int ct = 0; ct < 8; ++ct)
      f1a[ct] = __builtin_amdgcn_mfma_f32_16x16x32_bf16(
          af4[kk], *(const bf16x8*)(wf1t + (ct * 16 + li) * 128 + kk * 32 + lg * 8),
          f1a[ct], 0, 0, 0);
  epi_sp8(f1a, bf1, Sp, li, lg);

  // F2 + final residual
  #pragma unroll
  for (int kk = 0; kk < 4; ++kk)
    af4[kk] = *(const bf16x8*)(Sp + swz128(li, kk * 32 + lg * 8));
  f32x4 f2a[8];
  #pragma unroll
  for (int i = 0; i < 8; ++i) f2a[i] = (f32x4){0, 0, 0, 0};
  #pragma unroll
  for (int kk = 0; kk < 4; ++kk)
    #pragma unroll
    for (int ct = 0; ct < 8; ++ct)
      f2a[ct] = __builtin_amdgcn_mfma_f32_16x16x32_bf16(
          af4[kk], *(const bf16x8*)(wf2t + (ct * 16 + li) * 128 + kk * 32 + lg * 8),
          f2a[ct], 0, 0, 0);

  #pragma unroll
  for (int ct = 0; ct < 8; ++ct) {
    float bvv = bf2[ct * 16 + li];
    #pragma unroll
    for (int r = 0; r < 4; ++r)
      out[(R + lg * 4 + r) * DD + ct * 16 + li] =
          x2r[ct][r] + fmaxf(f2a[ct][r] + bvv, 0.0f);
  }
}

extern "C" void kernel_launch(void* const* d_in, const int* in_sizes, int n_in,
                              void* d_out, int out_size, void* d_ws, size_t ws_size,
                              hipStream_t stream) {
  const float* x   = (const float*)d_in[0];
  const float* ste = (const float*)d_in[1];
  const float* g1 = (const float*)d_in[3];
  const float* b1 = (const float*)d_in[4];
  const float* g2 = (const float*)d_in[5];
  const float* b2 = (const float*)d_in[6];
  const float* Wq = (const float*)d_in[7];   const float* bq  = (const float*)d_in[8];
  const float* Wk = (const float*)d_in[9];   const float* bk  = (const float*)d_in[10];
  const float* Wv = (const float*)d_in[11];  const float* bv  = (const float*)d_in[12];
  const float* Wo1 = (const float*)d_in[13]; const float* bo1 = (const float*)d_in[14];
  const float* Wo2 = (const float*)d_in[15]; const float* bo2 = (const float*)d_in[16];
  const float* Wf1 = (const float*)d_in[17]; const float* bf1 = (const float*)d_in[18];
  const float* Wf2 = (const float*)d_in[19]; const float* bf2 = (const float*)d_in[20];
  float* out = (float*)d_out;

  unsigned short* wsu = (unsigned short*)d_ws;
  unsigned short* wq_t  = wsu;             // [128][256]
  unsigned short* wk_t  = wsu + 32768;
  unsigned short* wv_t  = wsu + 65536;
  unsigned short* wo1_t = wsu + 98304;     // [128][128]
  unsigned short* wo2_t = wsu + 114688;
  unsigned short* wf1_t = wsu + 131072;
  unsigned short* wf2_t = wsu + 147456;
  unsigned short* ao    = wsu + 163840;    // [B*T*N][128] bf16 = 64 MB

  hipLaunchKernelGGL(wprep, dim3(128), dim3(256), 0, stream, Wq, wq_t, 256, 128);
  hipLaunchKernelGGL(wprep, dim3(128), dim3(256), 0, stream, Wk, wk_t, 256, 128);
  hipLaunchKernelGGL(wprep, dim3(128), dim3(256), 0, stream, Wv, wv_t, 256, 128);
  hipLaunchKernelGGL(wprep, dim3(64), dim3(256), 0, stream, Wo1, wo1_t, 128, 128);
  hipLaunchKernelGGL(wprep, dim3(64), dim3(256), 0, stream, Wo2, wo2_t, 128, 128);
  hipLaunchKernelGGL(wprep, dim3(64), dim3(256), 0, stream, Wf1, wf1_t, 128, 128);
  hipLaunchKernelGGL(wprep, dim3(64), dim3(256), 0, stream, Wf2, wf2_t, 128, 128);

  hipLaunchKernelGGL(attn_head, dim3(8 * NN), dim3(512), 0, stream,
                     x, ste, g1, b1, wq_t, bq, wk_t, bk, wv_t, bv, ao);
  hipLaunchKernelGGL(tail_ffn, dim3(8 * TT * NN / 64), dim3(256), 0, stream,
                     ao, x, g2, b2, wo1_t, bo1, wo2_t, bo2,
                     wf1_t, bf1, wf2_t, bf2, out);
}

// Round 15
// 422.378 us; speedup vs baseline: 1.5320x; 1.1325x over previous
//
#include <hip/hip_runtime.h>

#define TT 64
#define NN 512
#define DD 128

typedef __attribute__((ext_vector_type(8))) short bf16x8;
typedef __attribute__((ext_vector_type(4))) float f32x4;

__device__ __forceinline__ unsigned cvtpk(float lo, float hi) {
  unsigned r;
  asm("v_cvt_pk_bf16_f32 %0, %1, %2" : "=v"(r) : "v"(lo), "v"(hi));
  return r;
}

// XOR-swizzled LDS index helpers (units: unsigned short elements).
__device__ __forceinline__ int swz128(int row, int col) {
  return row * 128 + (((col >> 3) ^ (row & 15)) << 3) + (col & 7);
}
__device__ __forceinline__ int swz64(int row, int col) {
  return row * 64 + (((col >> 3) ^ (row & 7)) << 3) + (col & 7);
}

// Barrier with LDS-only drain: global loads stay in flight across it.
__device__ __forceinline__ void bar() {
  asm volatile("s_waitcnt lgkmcnt(0)" ::: "memory");
  __builtin_amdgcn_s_barrier();
  asm volatile("" ::: "memory");
}

// 16-lane (DPP-row) sum via row_ror butterflies — VALU pipe, no LDS traffic.
__device__ __forceinline__ float red16(float s) {
  int t;
  t = __builtin_amdgcn_update_dpp(0, __float_as_int(s), 0x121, 0xf, 0xf, false);
  s += __int_as_float(t);
  t = __builtin_amdgcn_update_dpp(0, __float_as_int(s), 0x122, 0xf, 0xf, false);
  s += __int_as_float(t);
  t = __builtin_amdgcn_update_dpp(0, __float_as_int(s), 0x124, 0xf, 0xf, false);
  s += __int_as_float(t);
  t = __builtin_amdgcn_update_dpp(0, __float_as_int(s), 0x128, 0xf, 0xf, false);
  s += __int_as_float(t);
  return s;
}

// transpose fp32 [K][N] -> bf16 [N][K]
__global__ void wprep(const float* __restrict__ src, unsigned short* __restrict__ dst,
                      int K, int Nn) {
  int idx = blockIdx.x * 256 + threadIdx.x;
  if (idx >= K * Nn) return;
  int n = idx / K, k = idx - n * K;
  float f = src[k * Nn + n];
  unsigned u = __float_as_uint(f);
  u += 0x7fffu + ((u >> 16) & 1u);
  dst[idx] = (unsigned short)(u >> 16);
}

#define KSCL 0.36067376022224085f   // 0.25 * log2(e), folded into K epilogue

// ============================ KERNEL A =====================================
// LN1 + col-strip QKV + wave-local causal attention -> AO (bf16) to global.
__global__ __launch_bounds__(512, 4)
void attn_head(const float* __restrict__ x_in, const float* __restrict__ ste,
               const float* __restrict__ g1, const float* __restrict__ b1,
               const unsigned short* __restrict__ wqt, const float* __restrict__ bq,
               const unsigned short* __restrict__ wkt, const float* __restrict__ bk,
               const unsigned short* __restrict__ wvt, const float* __restrict__ bv,
               unsigned short* __restrict__ aoG) {
  __shared__ __align__(16) unsigned short smem[32768];  // 64 KB

  const int tid = threadIdx.x;
  const int lane = tid & 63;
  const int w  = tid >> 6;         // wave 0..7
  const int lg = lane >> 4;        // 0..3
  const int li = lane & 15;
  const int hc = w * 16;           // col-strip base == head base

  const int blk = blockIdx.x;
  const int b = blk >> 9;          // N=512
  const int n = blk & 511;
  const int rs = NN * DD;
  const float* xbase = x_in + (b * TT * NN + n) * DD;
  const float* sbase = ste + (b * TT * NN + n) * DD;

  unsigned short* X2s = smem;
  unsigned short* Qb  = smem;
  unsigned short* AOb = smem + 8192;
  unsigned short* Kb  = smem + 16384;
  unsigned short* Vt  = smem + 24576;

  #define SWZ256(row, col) ((row) * 256 + ((((col) >> 3) ^ ((row) & 15)) << 3) + ((col) & 7))

  // ---------------- LN1 + STE -> X2 (all input loads hoisted) --------------
  {
    const int t0 = w * 8 + lg;
    const float* xr0 = xbase + t0 * rs + li * 8;
    const float* xr1 = xbase + (t0 + 4) * rs + li * 8;
    const float* sr0 = sbase + t0 * rs + li * 8;
    const float* sr1 = sbase + (t0 + 4) * rs + li * 8;
    float4 xA0 = *(const float4*)(xr0);
    float4 xB0 = *(const float4*)(xr0 + 4);
    float4 xA1 = *(const float4*)(xr1);
    float4 xB1 = *(const float4*)(xr1 + 4);
    float4 sA0 = *(const float4*)(sr0);
    float4 sB0 = *(const float4*)(sr0 + 4);
    float4 sA1 = *(const float4*)(sr1);
    float4 sB1 = *(const float4*)(sr1 + 4);
    float4 gA = *(const float4*)(g1 + li * 8);
    float4 gB = *(const float4*)(g1 + li * 8 + 4);
    float4 bA = *(const float4*)(b1 + li * 8);
    float4 bB = *(const float4*)(b1 + li * 8 + 4);

    {  // row t0
      float s1 = xA0.x + xA0.y + xA0.z + xA0.w + xB0.x + xB0.y + xB0.z + xB0.w;
      float s2 = xA0.x * xA0.x + xA0.y * xA0.y + xA0.z * xA0.z + xA0.w * xA0.w +
                 xB0.x * xB0.x + xB0.y * xB0.y + xB0.z * xB0.z + xB0.w * xB0.w;
      s1 = red16(s1); s2 = red16(s2);
      float mean = s1 * (1.0f / 128.0f);
      float var = fmaxf((s2 - s1 * mean) * (1.0f / 127.0f), 0.0f);  // ddof=1
      float inv = 1.0f / (sqrtf(var) + 1e-6f);
      unsigned o01 = cvtpk(gA.x * (xA0.x - mean) * inv + bA.x, gA.y * (xA0.y - mean) * inv + bA.y);
      unsigned o23 = cvtpk(gA.z * (xA0.z - mean) * inv + bA.z, gA.w * (xA0.w - mean) * inv + bA.w);
      unsigned o45 = cvtpk(gB.x * (xB0.x - mean) * inv + bB.x, gB.y * (xB0.y - mean) * inv + bB.y);
      unsigned o67 = cvtpk(gB.z * (xB0.z - mean) * inv + bB.z, gB.w * (xB0.w - mean) * inv + bB.w);
      *(uint4*)(X2s + SWZ256(t0, li * 8)) = (uint4){o01, o23, o45, o67};
    }
    {  // row t0+4
      float s1 = xA1.x + xA1.y + xA1.z + xA1.w + xB1.x + xB1.y + xB1.z + xB1.w;
      float s2 = xA1.x * xA1.x + xA1.y * xA1.y + xA1.z * xA1.z + xA1.w * xA1.w +
                 xB1.x * xB1.x + xB1.y * xB1.y + xB1.z * xB1.z + xB1.w * xB1.w;
      s1 = red16(s1); s2 = red16(s2);
      float mean = s1 * (1.0f / 128.0f);
      float var = fmaxf((s2 - s1 * mean) * (1.0f / 127.0f), 0.0f);
      float inv = 1.0f / (sqrtf(var) + 1e-6f);
      unsigned o01 = cvtpk(gA.x * (xA1.x - mean) * inv + bA.x, gA.y * (xA1.y - mean) * inv + bA.y);
      unsigned o23 = cvtpk(gA.z * (xA1.z - mean) * inv + bA.z, gA.w * (xA1.w - mean) * inv + bA.w);
      unsigned o45 = cvtpk(gB.x * (xB1.x - mean) * inv + bB.x, gB.y * (xB1.y - mean) * inv + bB.y);
      unsigned o67 = cvtpk(gB.z * (xB1.z - mean) * inv + bB.z, gB.w * (xB1.w - mean) * inv + bB.w);
      *(uint4*)(X2s + SWZ256(t0 + 4, li * 8)) = (uint4){o01, o23, o45, o67};
    }
    *(uint4*)(X2s + SWZ256(t0, 128 + li * 8)) =
        (uint4){cvtpk(sA0.x, sA0.y), cvtpk(sA0.z, sA0.w), cvtpk(sB0.x, sB0.y), cvtpk(sB0.z, sB0.w)};
    *(uint4*)(X2s + SWZ256(t0 + 4, 128 + li * 8)) =
        (uint4){cvtpk(sA1.x, sA1.y), cvtpk(sA1.z, sA1.w), cvtpk(sB1.x, sB1.y), cvtpk(sB1.z, sB1.w)};
  }

  bar();  // B0: X2 visible

  // ---------------- V-pass (cols hc..hc+15), immediate epi -> Vt -----------
  {
    const unsigned short* vB = wvt + hc * 256;
    f32x4 va[4];
    #pragma unroll
    for (int rg = 0; rg < 4; ++rg) va[rg] = (f32x4){0, 0, 0, 0};
    #pragma unroll
    for (int kk = 0; kk < 8; ++kk) {
      bf16x8 bc = *(const bf16x8*)(vB + li * 256 + kk * 32 + lg * 8);
      #pragma unroll
      for (int rg = 0; rg < 4; ++rg) {
        bf16x8 af = *(const bf16x8*)(X2s + SWZ256(rg * 16 + li, kk * 32 + lg * 8));
        va[rg] = __builtin_amdgcn_mfma_f32_16x16x32_bf16(af, bc, va[rg], 0, 0, 0);
      }
    }
    float bvv = bv[hc + li];
    int d = hc + li;
    #pragma unroll
    for (int rg = 0; rg < 4; ++rg) {
      float v0 = fmaxf(va[rg][0] + bvv, 0.0f);
      float v1 = fmaxf(va[rg][1] + bvv, 0.0f);
      float v2 = fmaxf(va[rg][2] + bvv, 0.0f);
      float v3 = fmaxf(va[rg][3] + bvv, 0.0f);
      uint2 pv; pv.x = cvtpk(v0, v1); pv.y = cvtpk(v2, v3);
      *(uint2*)(Vt + swz64(d, rg * 16 + lg * 4)) = pv;
    }
  }

  // ---------------- K-pass (cols hc..hc+15), immediate epi -> Kb -----------
  {
    const unsigned short* kB = wkt + hc * 256;
    f32x4 ka[4];
    #pragma unroll
    for (int rg = 0; rg < 4; ++rg) ka[rg] = (f32x4){0, 0, 0, 0};
    #pragma unroll
    for (int kk = 0; kk < 8; ++kk) {
      bf16x8 bc = *(const bf16x8*)(kB + li * 256 + kk * 32 + lg * 8);
      #pragma unroll
      for (int rg = 0; rg < 4; ++rg) {
        bf16x8 af = *(const bf16x8*)(X2s + SWZ256(rg * 16 + li, kk * 32 + lg * 8));
        ka[rg] = __builtin_amdgcn_mfma_f32_16x16x32_bf16(af, bc, ka[rg], 0, 0, 0);
      }
    }
    float bkv = bk[hc + li];
    int col = hc + li;
    #pragma unroll
    for (int rg = 0; rg < 4; ++rg) {
      float k0 = fmaxf(ka[rg][0] + bkv, 0.0f) * KSCL;
      float k1 = fmaxf(ka[rg][1] + bkv, 0.0f) * KSCL;
      float k2 = fmaxf(ka[rg][2] + bkv, 0.0f) * KSCL;
      float k3 = fmaxf(ka[rg][3] + bkv, 0.0f) * KSCL;
      unsigned p01 = cvtpk(k0, k1), p23 = cvtpk(k2, k3);
      Kb[swz128(rg * 16 + lg * 4 + 0, col)] = (unsigned short)p01;
      Kb[swz128(rg * 16 + lg * 4 + 1, col)] = (unsigned short)(p01 >> 16);
      Kb[swz128(rg * 16 + lg * 4 + 2, col)] = (unsigned short)p23;
      Kb[swz128(rg * 16 + lg * 4 + 3, col)] = (unsigned short)(p23 >> 16);
    }
  }

  // ---------------- Q-pass (cols hc..hc+15) --------------------------------
  f32x4 qa[4];
  #pragma unroll
  for (int rg = 0; rg < 4; ++rg) qa[rg] = (f32x4){0, 0, 0, 0};
  {
    const unsigned short* qB = wqt + hc * 256;
    #pragma unroll
    for (int kk = 0; kk < 8; ++kk) {
      bf16x8 bc = *(const bf16x8*)(qB + li * 256 + kk * 32 + lg * 8);
      #pragma unroll
      for (int rg = 0; rg < 4; ++rg) {
        bf16x8 af = *(const bf16x8*)(X2s + SWZ256(rg * 16 + li, kk * 32 + lg * 8));
        qa[rg] = __builtin_amdgcn_mfma_f32_16x16x32_bf16(af, bc, qa[rg], 0, 0, 0);
      }
    }
  }

  bar();  // B0e: ALL X2 reads done -> Qb/AOb overlays live

  // Q epilogue -> Qb (own col strip; consumed only by this wave)
  {
    float bqv = bq[hc + li];
    int col = hc + li;
    #pragma unroll
    for (int rg = 0; rg < 4; ++rg) {
      float v0 = fmaxf(qa[rg][0] + bqv, 0.0f);
      float v1 = fmaxf(qa[rg][1] + bqv, 0.0f);
      float v2 = fmaxf(qa[rg][2] + bqv, 0.0f);
      float v3 = fmaxf(qa[rg][3] + bqv, 0.0f);
      unsigned p01 = cvtpk(v0, v1), p23 = cvtpk(v2, v3);
      Qb[swz128(rg * 16 + lg * 4 + 0, col)] = (unsigned short)p01;
      Qb[swz128(rg * 16 + lg * 4 + 1, col)] = (unsigned short)(p01 >> 16);
      Qb[swz128(rg * 16 + lg * 4 + 2, col)] = (unsigned short)p23;
      Qb[swz128(rg * 16 + lg * 4 + 3, col)] = (unsigned short)(p23 >> 16);
    }
  }

  // ---------------- causal attention, head w (all strips wave-local) -------
  {
    const bf16x8 zf = (bf16x8){0, 0, 0, 0, 0, 0, 0, 0};
    bf16x8 kf[4], vf[2];
    #pragma unroll
    for (int pt = 0; pt < 4; ++pt)
      kf[pt] = (lg < 2) ? *(const bf16x8*)(Kb + swz128(pt * 16 + li, hc + lg * 8)) : zf;
    #pragma unroll
    for (int ks = 0; ks < 2; ++ks)
      vf[ks] = *(const bf16x8*)(Vt + swz64(hc + li, ks * 32 + lg * 8));

    #pragma unroll
    for (int qt = 0; qt < 4; ++qt) {
      bf16x8 qf = (lg < 2) ? *(const bf16x8*)(Qb + swz128(qt * 16 + li, hc + lg * 8)) : zf;
      f32x4 st[4];
      #pragma unroll
      for (int pt = 0; pt < 4; ++pt)
        if (pt <= qt)
          st[pt] = __builtin_amdgcn_mfma_f32_16x16x32_bf16(kf[pt], qf, (f32x4){0, 0, 0, 0}, 0, 0, 0);

      float ssum = 0.0f;
      unsigned pa[4], pb[4];
      #pragma unroll
      for (int pt = 0; pt < 4; ++pt) {
        if (pt > qt) { pa[pt] = 0; pb[pt] = 0; continue; }
        float e0 = exp2f(st[pt][0]);
        float e1 = exp2f(st[pt][1]);
        float e2 = exp2f(st[pt][2]);
        float e3 = exp2f(st[pt][3]);
        if (pt == qt) {  // diagonal tile: mask p_local > q_local
          e0 = (4 * lg + 0 > li) ? 0.0f : e0;
          e1 = (4 * lg + 1 > li) ? 0.0f : e1;
          e2 = (4 * lg + 2 > li) ? 0.0f : e2;
          e3 = (4 * lg + 3 > li) ? 0.0f : e3;
        }
        ssum += e0 + e1 + e2 + e3;
        pa[pt] = cvtpk(e0, e1);
        pb[pt] = cvtpk(e2, e3);
      }
      ssum += __shfl_xor(ssum, 16, 64);
      ssum += __shfl_xor(ssum, 32, 64);
      float rinv = 1.0f / ssum;

      f32x4 oa = (f32x4){0, 0, 0, 0};
      #pragma unroll
      for (int ks = 0; ks < 2; ++ks) {
        if (ks * 2 > qt) continue;
        unsigned x = pa[2 * ks], y = pa[2 * ks + 1];
        asm("v_permlane32_swap_b32 %0, %1" : "+v"(x), "+v"(y));
        asm("v_permlane16_swap_b32 %0, %1" : "+v"(x), "+v"(y));
        unsigned u2 = pb[2 * ks], v2 = pb[2 * ks + 1];
        asm("v_permlane32_swap_b32 %0, %1" : "+v"(u2), "+v"(v2));
        asm("v_permlane16_swap_b32 %0, %1" : "+v"(u2), "+v"(v2));
        union { unsigned uw[4]; bf16x8 h; } pu;
        pu.uw[0] = x; pu.uw[1] = u2; pu.uw[2] = y; pu.uw[3] = v2;
        oa = __builtin_amdgcn_mfma_f32_16x16x32_bf16(vf[ks], pu.h, oa, 0, 0, 0);
      }
      uint2 ov;
      ov.x = cvtpk(oa[0] * rinv, oa[1] * rinv);
      ov.y = cvtpk(oa[2] * rinv, oa[3] * rinv);
      *(uint2*)(AOb + swz128(qt * 16 + li, hc + lg * 4)) = ov;
    }
  }

  bar();  // B2: AO strips visible

  // Coalesced AO store: wave w -> rows w*8..w*8+7, 16 lanes x 16B per row
  #pragma unroll
  for (int pass = 0; pass < 2; ++pass) {
    int t = w * 8 + pass * 4 + lg;
    uint4 v = *(const uint4*)(AOb + swz128(t, li * 8));
    *(uint4*)(aoG + ((b * TT + t) * NN + n) * DD + li * 8) = v;
  }
  #undef SWZ256
}

// ============================ KERNEL B =====================================
// Barrier-free tail, HALF-WIDTH passes (acc[4] not acc[8]) + x2 parked in
// per-wave LDS (bf16) -> peak arch VGPR ~55, fits the allocator's preferred
// 64-reg/8-wave point with ZERO spills (R13/R14: 160-240 MB spill stores).
__device__ __forceinline__ void epi4h(const f32x4 acc[4], const float* __restrict__ bias,
                                      unsigned short* Sp, int c0, int li, int lg) {
  #pragma unroll
  for (int ct = 0; ct < 4; ++ct) {
    int col = c0 + ct * 16 + li;
    float bv = bias[col];
    float v0 = fmaxf(acc[ct][0] + bv, 0.0f);
    float v1 = fmaxf(acc[ct][1] + bv, 0.0f);
    float v2 = fmaxf(acc[ct][2] + bv, 0.0f);
    float v3 = fmaxf(acc[ct][3] + bv, 0.0f);
    unsigned p01 = cvtpk(v0, v1), p23 = cvtpk(v2, v3);
    Sp[swz128(lg * 4 + 0, col)] = (unsigned short)p01;
    Sp[swz128(lg * 4 + 1, col)] = (unsigned short)(p01 >> 16);
    Sp[swz128(lg * 4 + 2, col)] = (unsigned short)p23;
    Sp[swz128(lg * 4 + 3, col)] = (unsigned short)(p23 >> 16);
  }
}

__global__ __launch_bounds__(256)
void tail_ffn(const unsigned short* __restrict__ aoG, const float* __restrict__ x_in,
              const float* __restrict__ g2, const float* __restrict__ b2,
              const unsigned short* __restrict__ wo1t, const float* __restrict__ bo1,
              const unsigned short* __restrict__ wo2t, const float* __restrict__ bo2,
              const unsigned short* __restrict__ wf1t, const float* __restrict__ bf1,
              const unsigned short* __restrict__ wf2t, const float* __restrict__ bf2,
              float* __restrict__ out) {
  __shared__ __align__(16) unsigned short smem[16384];  // 32 KB
  const int tid = threadIdx.x;
  const int lane = tid & 63;
  const int w  = tid >> 6;          // wave 0..3
  const int lg = lane >> 4;
  const int li = lane & 15;
  unsigned short* Sp  = smem + w * 4096;         // wave-private [16][128]
  unsigned short* Sp2 = smem + w * 4096 + 2048;  // wave-private x2 (bf16)
  const int R = blockIdx.x * 64 + w * 16;        // flat row base

  // ---- O1 (two 64-col halves) ----
  bf16x8 af4[4];
  #pragma unroll
  for (int kk = 0; kk < 4; ++kk)
    af4[kk] = *(const bf16x8*)(aoG + (R + li) * DD + kk * 32 + lg * 8);
  #pragma unroll
  for (int h = 0; h < 2; ++h) {
    f32x4 acc[4];
    #pragma unroll
    for (int i = 0; i < 4; ++i) acc[i] = (f32x4){0, 0, 0, 0};
    #pragma unroll
    for (int kk = 0; kk < 4; ++kk)
      #pragma unroll
      for (int ct = 0; ct < 4; ++ct)
        acc[ct] = __builtin_amdgcn_mfma_f32_16x16x32_bf16(
            af4[kk],
            *(const bf16x8*)(wo1t + (h * 64 + ct * 16 + li) * 128 + kk * 32 + lg * 8),
            acc[ct], 0, 0, 0);
    epi4h(acc, bo1, Sp, h * 64, li, lg);
  }

  // ---- O2 + residual (per half; xr loaded just-in-time) ----
  #pragma unroll
  for (int kk = 0; kk < 4; ++kk)
    af4[kk] = *(const bf16x8*)(Sp + swz128(li, kk * 32 + lg * 8));
  float s1p[4] = {0, 0, 0, 0}, s2p[4] = {0, 0, 0, 0};
  #pragma unroll
  for (int h = 0; h < 2; ++h) {
    float xrh[4][4];
    #pragma unroll
    for (int ct = 0; ct < 4; ++ct)
      #pragma unroll
      for (int r = 0; r < 4; ++r)
        xrh[ct][r] = x_in[(R + lg * 4 + r) * DD + h * 64 + ct * 16 + li];
    f32x4 acc[4];
    #pragma unroll
    for (int i = 0; i < 4; ++i) acc[i] = (f32x4){0, 0, 0, 0};
    #pragma unroll
    for (int kk = 0; kk < 4; ++kk)
      #pragma unroll
      for (int ct = 0; ct < 4; ++ct)
        acc[ct] = __builtin_amdgcn_mfma_f32_16x16x32_bf16(
            af4[kk],
            *(const bf16x8*)(wo2t + (h * 64 + ct * 16 + li) * 128 + kk * 32 + lg * 8),
            acc[ct], 0, 0, 0);
    // x2 = acc + bo2 + x ; accumulate LN2 partials; park x2 as bf16 in Sp2
    #pragma unroll
    for (int ct = 0; ct < 4; ++ct) {
      int col = h * 64 + ct * 16 + li;
      float bvv = bo2[col];
      float v0 = acc[ct][0] + bvv + xrh[ct][0];
      float v1 = acc[ct][1] + bvv + xrh[ct][1];
      float v2 = acc[ct][2] + bvv + xrh[ct][2];
      float v3 = acc[ct][3] + bvv + xrh[ct][3];
      s1p[0] += v0; s2p[0] += v0 * v0;
      s1p[1] += v1; s2p[1] += v1 * v1;
      s1p[2] += v2; s2p[2] += v2 * v2;
      s1p[3] += v3; s2p[3] += v3 * v3;
      unsigned p01 = cvtpk(v0, v1), p23 = cvtpk(v2, v3);
      Sp2[swz128(lg * 4 + 0, col)] = (unsigned short)p01;
      Sp2[swz128(lg * 4 + 1, col)] = (unsigned short)(p01 >> 16);
      Sp2[swz128(lg * 4 + 2, col)] = (unsigned short)p23;
      Sp2[swz128(lg * 4 + 3, col)] = (unsigned short)(p23 >> 16);
    }
  }

  // ---- LN2 (wave-local; stats from fp32 partials) ----
  float mean_[4], inv_[4];
  #pragma unroll
  for (int r = 0; r < 4; ++r) {
    float s1 = red16(s1p[r]);
    float s2 = red16(s2p[r]);
    float mean = s1 * (1.0f / 128.0f);
    float var = fmaxf((s2 - s1 * mean) * (1.0f / 127.0f), 0.0f);  // ddof=1
    mean_[r] = mean;
    inv_[r] = 1.0f / (sqrtf(var) + 1e-6f);
  }
  // Xn2 -> Sp (x2 read back from Sp2; same-wave DS in-order)
  #pragma unroll
  for (int ct = 0; ct < 8; ++ct) {
    int col = ct * 16 + li;
    float gv = g2[col], bv2 = b2[col];
    float x0 = __uint_as_float((unsigned)Sp2[swz128(lg * 4 + 0, col)] << 16);
    float x1 = __uint_as_float((unsigned)Sp2[swz128(lg * 4 + 1, col)] << 16);
    float x2v = __uint_as_float((unsigned)Sp2[swz128(lg * 4 + 2, col)] << 16);
    float x3 = __uint_as_float((unsigned)Sp2[swz128(lg * 4 + 3, col)] << 16);
    unsigned p01 = cvtpk(gv * (x0 - mean_[0]) * inv_[0] + bv2,
                         gv * (x1 - mean_[1]) * inv_[1] + bv2);
    unsigned p23 = cvtpk(gv * (x2v - mean_[2]) * inv_[2] + bv2,
                         gv * (x3 - mean_[3]) * inv_[3] + bv2);
    Sp[swz128(lg * 4 + 0, col)] = (unsigned short)p01;
    Sp[swz128(lg * 4 + 1, col)] = (unsigned short)(p01 >> 16);
    Sp[swz128(lg * 4 + 2, col)] = (unsigned short)p23;
    Sp[swz128(lg * 4 + 3, col)] = (unsigned short)(p23 >> 16);
  }

  // ---- F1 (two halves; af4 read from Sp=Xn2 before Hf overwrites) ----
  #pragma unroll
  for (int kk = 0; kk < 4; ++kk)
    af4[kk] = *(const bf16x8*)(Sp + swz128(li, kk * 32 + lg * 8));
  #pragma unroll
  for (int h = 0; h < 2; ++h) {
    f32x4 acc[4];
    #pragma unroll
    for (int i = 0; i < 4; ++i) acc[i] = (f32x4){0, 0, 0, 0};
    #pragma unroll
    for (int kk = 0; kk < 4; ++kk)
      #pragma unroll
      for (int ct = 0; ct < 4; ++ct)
        acc[ct] = __builtin_amdgcn_mfma_f32_16x16x32_bf16(
            af4[kk],
            *(const bf16x8*)(wf1t + (h * 64 + ct * 16 + li) * 128 + kk * 32 + lg * 8),
            acc[ct], 0, 0, 0);
    epi4h(acc, bf1, Sp, h * 64, li, lg);
  }

  // ---- F2 (two halves) + final residual from Sp2 ----
  #pragma unroll
  for (int kk = 0; kk < 4; ++kk)
    af4[kk] = *(const bf16x8*)(Sp + swz128(li, kk * 32 + lg * 8));
  #pragma unroll
  for (int h = 0; h < 2; ++h) {
    f32x4 acc[4];
    #pragma unroll
    for (int i = 0; i < 4; ++i) acc[i] = (f32x4){0, 0, 0, 0};
    #pragma unroll
    for (int kk = 0; kk < 4; ++kk)
      #pragma unroll
      for (int ct = 0; ct < 4; ++ct)
        acc[ct] = __builtin_amdgcn_mfma_f32_16x16x32_bf16(
            af4[kk],
            *(const bf16x8*)(wf2t + (h * 64 + ct * 16 + li) * 128 + kk * 32 + lg * 8),
            acc[ct], 0, 0, 0);
    #pragma unroll
    for (int ct = 0; ct < 4; ++ct) {
      int col = h * 64 + ct * 16 + li;
      float bvv = bf2[col];
      #pragma unroll
      for (int r = 0; r < 4; ++r) {
        float x2v = __uint_as_float((unsigned)Sp2[swz128(lg * 4 + r, col)] << 16);
        out[(R + lg * 4 + r) * DD + col] = x2v + fmaxf(acc[ct][r] + bvv, 0.0f);
      }
    }
  }
}

extern "C" void kernel_launch(void* const* d_in, const int* in_sizes, int n_in,
                              void* d_out, int out_size, void* d_ws, size_t ws_size,
                              hipStream_t stream) {
  const float* x   = (const float*)d_in[0];
  const float* ste = (const float*)d_in[1];
  const float* g1 = (const float*)d_in[3];
  const float* b1 = (const float*)d_in[4];
  const float* g2 = (const float*)d_in[5];
  const float* b2 = (const float*)d_in[6];
  const float* Wq = (const float*)d_in[7];   const float* bq  = (const float*)d_in[8];
  const float* Wk = (const float*)d_in[9];   const float* bk  = (const float*)d_in[10];
  const float* Wv = (const float*)d_in[11];  const float* bv  = (const float*)d_in[12];
  const float* Wo1 = (const float*)d_in[13]; const float* bo1 = (const float*)d_in[14];
  const float* Wo2 = (const float*)d_in[15]; const float* bo2 = (const float*)d_in[16];
  const float* Wf1 = (const float*)d_in[17]; const float* bf1 = (const float*)d_in[18];
  const float* Wf2 = (const float*)d_in[19]; const float* bf2 = (const float*)d_in[20];
  float* out = (float*)d_out;

  unsigned short* wsu = (unsigned short*)d_ws;
  unsigned short* wq_t  = wsu;             // [128][256]
  unsigned short* wk_t  = wsu + 32768;
  unsigned short* wv_t  = wsu + 65536;
  unsigned short* wo1_t = wsu + 98304;     // [128][128]
  unsigned short* wo2_t = wsu + 114688;
  unsigned short* wf1_t = wsu + 131072;
  unsigned short* wf2_t = wsu + 147456;
  unsigned short* ao    = wsu + 163840;    // [B*T*N][128] bf16 = 64 MB

  hipLaunchKernelGGL(wprep, dim3(128), dim3(256), 0, stream, Wq, wq_t, 256, 128);
  hipLaunchKernelGGL(wprep, dim3(128), dim3(256), 0, stream, Wk, wk_t, 256, 128);
  hipLaunchKernelGGL(wprep, dim3(128), dim3(256), 0, stream, Wv, wv_t, 256, 128);
  hipLaunchKernelGGL(wprep, dim3(64), dim3(256), 0, stream, Wo1, wo1_t, 128, 128);
  hipLaunchKernelGGL(wprep, dim3(64), dim3(256), 0, stream, Wo2, wo2_t, 128, 128);
  hipLaunchKernelGGL(wprep, dim3(64), dim3(256), 0, stream, Wf1, wf1_t, 128, 128);
  hipLaunchKernelGGL(wprep, dim3(64), dim3(256), 0, stream, Wf2, wf2_t, 128, 128);

  hipLaunchKernelGGL(attn_head, dim3(8 * NN), dim3(512), 0, stream,
                     x, ste, g1, b1, wq_t, bq, wk_t, bk, wv_t, bv, ao);
  hipLaunchKernelGGL(tail_ffn, dim3(8 * TT * NN / 64), dim3(256), 0, stream,
                     ao, x, g2, b2, wo1_t, bo1, wo2_t, bo2,
                     wf1_t, bf1, wf2_t, bf2, out);
}